// Round 1
// baseline (617.048 us; speedup 1.0000x reference)
//
#include <hip/hip_runtime.h>

// ---------------------------------------------------------------------------
// SpatioTemporalBlock: biLSTM -> temporal MHA -> (collapsed) GAT -> fusion
// B=16 S=128 F=64 H=256 HEADS=4 DH=64 AH=128 D2=512
// FP32 inputs/outputs; MFMA operands converted f32->bf16 at staging.
// GAT collapses: broadcast node features => uniform alpha => dense layers.
//
// LSTM v2: wave-autonomous, zero-LDS, zero-barrier inner loop.
//   - Whh/Wih fragments live in registers (loaded once per lane).
//   - Gate rows remapped: wave w owns cols q*16+w*4..+3, all 4 gates
//     (N-index n = gate*4 + c2), so i/f/g/o for one (batch,col) sit in
//     lanes differing in bits 2-3 of lane&15 -> gathered by __shfl_xor.
//   - The sc1 poison polls load exactly the MFMA A-fragments; on success
//     the returned registers feed the 8 Whh MFMAs directly.
//   - x-part (2 MFMAs) computed from direct global loads before the poll
//     (hidden under the wait). Bias folded per-lane.
// Cross-WG sync protocol unchanged: hbuf write-once ring
// [128 steps][2 dir][16 b][256 c] bf16, memset 0xFF per launch; h published
// as packed u32 via relaxed agent atomics; readers poll with sc1 dwordx4
// until != 0xFFFFFFFF (h bounded by sigmoid*tanh => never the NaN pattern).
// ---------------------------------------------------------------------------

typedef unsigned short u16;
typedef unsigned int u32;
typedef __bf16 bf16x8 __attribute__((ext_vector_type(8)));
typedef float f32x4 __attribute__((ext_vector_type(4)));
typedef unsigned short ushort8v __attribute__((ext_vector_type(8)));
typedef unsigned int uint4v __attribute__((ext_vector_type(4)));

#define BN_INV_F 0.9999950000374997f
#define POISON 0xFFFFFFFFu

__device__ __forceinline__ float b2f(u16 u) {
  union { float f; unsigned int i; } v;
  v.i = ((unsigned int)u) << 16;
  return v.f;
}
__device__ __forceinline__ u16 f2b(float f) {
  union { float f; unsigned int i; } v;
  v.f = f;
  unsigned int x = v.i;
  unsigned int r = (x + 0x7FFFu + ((x >> 16) & 1u)) >> 16;
  return (u16)r;
}
__device__ __forceinline__ f32x4 mfma16(ushort8v a, ushort8v b, f32x4 c) {
  return __builtin_amdgcn_mfma_f32_16x16x32_bf16(
      __builtin_bit_cast(bf16x8, a), __builtin_bit_cast(bf16x8, b), c, 0, 0, 0);
}
__device__ __forceinline__ float sigm(float x) { return 1.f / (1.f + __expf(-x)); }
__device__ __forceinline__ float tanh_f(float x) {
  float e = __expf(2.f * x);
  return 1.f - 2.f / (e + 1.f);
}
__device__ __forceinline__ u32 umaxu(u32 a, u32 b) { return a > b ? a : b; }

// ---------------------------------------------------------------------------
// Kernel 1: bidirectional LSTM. grid = 32 blocks: dir = bx>>4, chunk q = bx&15.
// Wave w of WG (d,q) owns h-cols q*16 + w*4 .. +3 (all 4 gates).
// Per lane (quad=ln>>4, col16=ln&15): gate row G = (col16>>2)*256 + q*16 +
// w*4 + (col16&3); Whh/Wih fragments for that row held in registers.
// Per step: x-part MFMAs (global loads, hidden), poll h(t) via 8 coalesced
// sc1 dwordx4 loads (these ARE the A-fragments), 8 Whh MFMAs, shuffle-gather
// gates, f32 gate math in 4 owner lanes/quad, publish via relaxed agent
// atomic u32 stores. No LDS, no __syncthreads.
// ---------------------------------------------------------------------------
__global__ __launch_bounds__(256) void lstm_kernel(
    const float* __restrict__ x,
    const float* __restrict__ Wih0, const float* __restrict__ Whh0,
    const float* __restrict__ bih0, const float* __restrict__ bhh0,
    const float* __restrict__ Wih1, const float* __restrict__ Whh1,
    const float* __restrict__ bih1, const float* __restrict__ bhh1,
    u32* __restrict__ hbuf,   // [128][2][16][128] u32 view (poisoned 0xFF)
    u16* __restrict__ tb)     // [16][128][512] bf16
{
  const int tid = threadIdx.x;
  const int bx = blockIdx.x;
  const int d = bx >> 4;
  const int q = bx & 15;
  const float* Wih = d ? Wih1 : Wih0;
  const float* Whh = d ? Whh1 : Whh0;
  const float* bih = d ? bih1 : bih0;
  const float* bhh = d ? bhh1 : bhh0;

  const int w = tid >> 6;
  const int ln = tid & 63;
  const int col16 = ln & 15;
  const int quad = ln >> 4;

  // this lane's gate row
  const int G = (col16 >> 2) * 256 + q * 16 + w * 4 + (col16 & 3);

  // ---- stage weights into registers (bf16 fragments) ----
  ushort8v whh_f[8];
#pragma unroll
  for (int kt = 0; kt < 8; kt++) {
    const float4* src = (const float4*)(Whh + G * 256 + kt * 32 + quad * 8);
    float4 v0 = src[0], v1 = src[1];
    ushort8v t8;
    t8[0] = f2b(v0.x); t8[1] = f2b(v0.y); t8[2] = f2b(v0.z); t8[3] = f2b(v0.w);
    t8[4] = f2b(v1.x); t8[5] = f2b(v1.y); t8[6] = f2b(v1.z); t8[7] = f2b(v1.w);
    whh_f[kt] = t8;
  }
  ushort8v wih_f[2];
#pragma unroll
  for (int kt = 0; kt < 2; kt++) {
    const float4* src = (const float4*)(Wih + G * 64 + kt * 32 + quad * 8);
    float4 v0 = src[0], v1 = src[1];
    ushort8v t8;
    t8[0] = f2b(v0.x); t8[1] = f2b(v0.y); t8[2] = f2b(v0.z); t8[3] = f2b(v0.w);
    t8[4] = f2b(v1.x); t8[5] = f2b(v1.y); t8[6] = f2b(v1.z); t8[7] = f2b(v1.w);
    wih_f[kt] = t8;
  }
  const float bias = bih[G] + bhh[G];

  f32x4 c_reg = {0.f, 0.f, 0.f, 0.f};
  const int colbase = q * 16 + w * 4 + col16;  // only meaningful for owners

  for (int t = 0; t < 128; t++) {
    const int pos = d ? (127 - t) : t;

    // ---- x-part: direct global loads (L1/L2-hot), f32->bf16, 2 MFMAs ----
    ushort8v ax0, ax1;
    {
      const float4* xs = (const float4*)(x + (col16 * 128 + pos) * 64 + quad * 8);
      float4 v0 = xs[0], v1 = xs[1];          // k = quad*8 .. +7
      const float4* xs1 = (const float4*)(x + (col16 * 128 + pos) * 64 + 32 + quad * 8);
      float4 v2 = xs1[0], v3 = xs1[1];        // k = 32 + quad*8 .. +7
      ax0[0] = f2b(v0.x); ax0[1] = f2b(v0.y); ax0[2] = f2b(v0.z); ax0[3] = f2b(v0.w);
      ax0[4] = f2b(v1.x); ax0[5] = f2b(v1.y); ax0[6] = f2b(v1.z); ax0[7] = f2b(v1.w);
      ax1[0] = f2b(v2.x); ax1[1] = f2b(v2.y); ax1[2] = f2b(v2.z); ax1[3] = f2b(v2.w);
      ax1[4] = f2b(v3.x); ax1[5] = f2b(v3.y); ax1[6] = f2b(v3.z); ax1[7] = f2b(v3.w);
    }
    f32x4 acc = {0.f, 0.f, 0.f, 0.f};
    acc = mfma16(ax0, wih_f[0], acc);
    acc = mfma16(ax1, wih_f[1], acc);

    if (t > 0) {
      // ---- poll h(t): 8 sc1 dwordx4 = exactly this lane's A-fragments ----
      const u32* hb = hbuf + (t * 2 + d) * 2048 + col16 * 128 + quad * 4;
      uint4v p0, p1, p2, p3, p4, p5, p6, p7;
      for (;;) {
        asm volatile(
            "global_load_dwordx4 %0, %8, off sc1\n\t"
            "global_load_dwordx4 %1, %8, off offset:64 sc1\n\t"
            "global_load_dwordx4 %2, %8, off offset:128 sc1\n\t"
            "global_load_dwordx4 %3, %8, off offset:192 sc1\n\t"
            "global_load_dwordx4 %4, %8, off offset:256 sc1\n\t"
            "global_load_dwordx4 %5, %8, off offset:320 sc1\n\t"
            "global_load_dwordx4 %6, %8, off offset:384 sc1\n\t"
            "global_load_dwordx4 %7, %8, off offset:448 sc1\n\t"
            "s_waitcnt vmcnt(0)"
            : "=v"(p0), "=v"(p1), "=v"(p2), "=v"(p3),
              "=v"(p4), "=v"(p5), "=v"(p6), "=v"(p7)
            : "v"(hb)
            : "memory");
        // any word == 0xFFFFFFFF (both-halves bf16 NaN) iff still poisoned;
        // detect via max-reduce: max == 0xFFFFFFFF iff ANY word is poison.
        u32 mx = p0.x;
        mx = umaxu(mx, p0.y); mx = umaxu(mx, p0.z); mx = umaxu(mx, p0.w);
        mx = umaxu(mx, p1.x); mx = umaxu(mx, p1.y); mx = umaxu(mx, p1.z); mx = umaxu(mx, p1.w);
        mx = umaxu(mx, p2.x); mx = umaxu(mx, p2.y); mx = umaxu(mx, p2.z); mx = umaxu(mx, p2.w);
        mx = umaxu(mx, p3.x); mx = umaxu(mx, p3.y); mx = umaxu(mx, p3.z); mx = umaxu(mx, p3.w);
        mx = umaxu(mx, p4.x); mx = umaxu(mx, p4.y); mx = umaxu(mx, p4.z); mx = umaxu(mx, p4.w);
        mx = umaxu(mx, p5.x); mx = umaxu(mx, p5.y); mx = umaxu(mx, p5.z); mx = umaxu(mx, p5.w);
        mx = umaxu(mx, p6.x); mx = umaxu(mx, p6.y); mx = umaxu(mx, p6.z); mx = umaxu(mx, p6.w);
        mx = umaxu(mx, p7.x); mx = umaxu(mx, p7.y); mx = umaxu(mx, p7.z); mx = umaxu(mx, p7.w);
        if (mx != POISON) break;
      }
      acc = mfma16(__builtin_bit_cast(ushort8v, p0), whh_f[0], acc);
      acc = mfma16(__builtin_bit_cast(ushort8v, p1), whh_f[1], acc);
      acc = mfma16(__builtin_bit_cast(ushort8v, p2), whh_f[2], acc);
      acc = mfma16(__builtin_bit_cast(ushort8v, p3), whh_f[3], acc);
      acc = mfma16(__builtin_bit_cast(ushort8v, p4), whh_f[4], acc);
      acc = mfma16(__builtin_bit_cast(ushort8v, p5), whh_f[5], acc);
      acc = mfma16(__builtin_bit_cast(ushort8v, p6), whh_f[6], acc);
      acc = mfma16(__builtin_bit_cast(ushort8v, p7), whh_f[7], acc);
    }

    // ---- gather gates via shuffles (all lanes execute) ----
    float zz[4], zf[4], zg[4], zo[4];
#pragma unroll
    for (int r = 0; r < 4; r++) zz[r] = acc[r] + bias;
#pragma unroll
    for (int r = 0; r < 4; r++) {
      zf[r] = __shfl_xor(zz[r], 4);
      zg[r] = __shfl_xor(zz[r], 8);
      zo[r] = __shfl_xor(zz[r], 12);
    }

    // ---- gate math (torch order i,f,g,o); owners are col16 < 4 ----
    u32 word[4];
#pragma unroll
    for (int r = 0; r < 4; r++) {
      float si = sigm(zz[r]);
      float sf = sigm(zf[r]);
      float so = sigm(zo[r]);
      float tg = tanh_f(zg[r]);
      float cc = sf * c_reg[r] + si * tg;
      c_reg[r] = cc;
      float hv = so * tanh_f(cc);
      u32 my = (u32)f2b(hv);
      u32 hi = ((u32)__shfl_xor((int)my, 1)) & 0xFFFFu;  // partner col (c2^1)
      word[r] = my | (hi << 16);
    }

    if (col16 == 0 || col16 == 2) {
#pragma unroll
      for (int r = 0; r < 4; r++) {
        const int batch = quad * 4 + r;
        *(u32*)&tb[(batch * 128 + pos) * 512 + d * 256 + colbase] = word[r];
        if (t < 127) {
          u32* dst = hbuf + ((t + 1) * 2 + d) * 2048 + batch * 128 + (colbase >> 1);
          __hip_atomic_store(dst, word[r], __ATOMIC_RELAXED,
                             __HIP_MEMORY_SCOPE_AGENT);
        }
      }
    }
  }
}

// ---------------------------------------------------------------------------
// Kernel 2: QKV projection.  out = t @ W^T + bias, M=2048 N=512 K=512.
// grid = (32 Mtiles, 8 Ntiles, 3 which). Q,K,V stored bf16.
// ---------------------------------------------------------------------------
__global__ __launch_bounds__(256) void qkv_kernel(
    const u16* __restrict__ tb,
    const float* __restrict__ Wq, const float* __restrict__ bq,
    const float* __restrict__ Wk, const float* __restrict__ bk,
    const float* __restrict__ Wv, const float* __restrict__ bv,
    u16* __restrict__ Qb, u16* __restrict__ Kb, u16* __restrict__ Vb)
{
  const int tid = threadIdx.x;
  const int bxm = blockIdx.x, byn = blockIdx.y, bz = blockIdx.z;
  const float* W = (bz == 0) ? Wq : ((bz == 1) ? Wk : Wv);
  const float* bias = (bz == 0) ? bq : ((bz == 1) ? bk : bv);
  u16* outp = (bz == 0) ? Qb : ((bz == 1) ? Kb : Vb);

  __shared__ u16 a_s[64][40];
  __shared__ u16 b_s[64][40];
  const int w = tid >> 6, ln = tid & 63, col16 = ln & 15, quad = ln >> 4;

  f32x4 acc[4];
#pragma unroll
  for (int n = 0; n < 4; n++) acc[n] = (f32x4){0.f, 0.f, 0.f, 0.f};

  for (int kt = 0; kt < 16; kt++) {
    int r = tid >> 2, seg = tid & 3;
    *(ushort8v*)&a_s[r][seg * 8] =
        *(const ushort8v*)(tb + (bxm * 64 + r) * 512 + kt * 32 + seg * 8);
    const float4* wsrc = (const float4*)(W + (byn * 64 + r) * 512 + kt * 32 + seg * 8);
    float4 w0 = wsrc[0], w1 = wsrc[1];
    b_s[r][seg * 8 + 0] = f2b(w0.x);
    b_s[r][seg * 8 + 1] = f2b(w0.y);
    b_s[r][seg * 8 + 2] = f2b(w0.z);
    b_s[r][seg * 8 + 3] = f2b(w0.w);
    b_s[r][seg * 8 + 4] = f2b(w1.x);
    b_s[r][seg * 8 + 5] = f2b(w1.y);
    b_s[r][seg * 8 + 6] = f2b(w1.z);
    b_s[r][seg * 8 + 7] = f2b(w1.w);
    __syncthreads();
    ushort8v av = *(const ushort8v*)&a_s[w * 16 + col16][quad * 8];
#pragma unroll
    for (int n = 0; n < 4; n++) {
      ushort8v bvv = *(const ushort8v*)&b_s[n * 16 + col16][quad * 8];
      acc[n] = mfma16(av, bvv, acc[n]);
    }
    __syncthreads();
  }
#pragma unroll
  for (int n = 0; n < 4; n++) {
    float bs = bias[byn * 64 + n * 16 + col16];
#pragma unroll
    for (int reg = 0; reg < 4; reg++) {
      int row = bxm * 64 + w * 16 + quad * 4 + reg;
      outp[row * 512 + byn * 64 + n * 16 + col16] = f2b(acc[n][reg] + bs);
    }
  }
}

// ---------------------------------------------------------------------------
// Kernel 3: scores + softmax -> attn (d_out, f32). grid = (16 b, 4 h, 2 qhalf).
// ---------------------------------------------------------------------------
__global__ __launch_bounds__(256) void attn_kernel(
    const u16* __restrict__ Qb, const u16* __restrict__ Kb,
    float* __restrict__ attn_out)
{
  const int b = blockIdx.x, h = blockIdx.y, half = blockIdx.z;
  const int tid = threadIdx.x;
  __shared__ __align__(16) char smem[52224];
  u16 (*q_s)[136] = (u16(*)[136])smem;
  u16 (*k_s)[136] = (u16(*)[136])(smem + 17408);
  float (*sc)[132] = (float(*)[132])smem;  // reused after MFMA

  const int w = tid >> 6, ln = tid & 63, col16 = ln & 15, quad = ln >> 4;
  {
    int r = tid >> 2, seg = tid & 3;
    const u16* src = Qb + (b * 128 + half * 64 + r) * 512 + h * 128 + seg * 32;
#pragma unroll
    for (int i = 0; i < 4; i++)
      *(ushort8v*)&q_s[r][seg * 32 + i * 8] = *(const ushort8v*)(src + i * 8);
    int r2 = tid >> 1, sg = tid & 1;
    const u16* src2 = Kb + (b * 128 + r2) * 512 + h * 128 + sg * 64;
#pragma unroll
    for (int i = 0; i < 8; i++)
      *(ushort8v*)&k_s[r2][sg * 64 + i * 8] = *(const ushort8v*)(src2 + i * 8);
  }
  __syncthreads();

  f32x4 acc[8];
#pragma unroll
  for (int n = 0; n < 8; n++) acc[n] = (f32x4){0.f, 0.f, 0.f, 0.f};
#pragma unroll
  for (int kd = 0; kd < 4; kd++) {
    ushort8v av = *(const ushort8v*)&q_s[w * 16 + col16][kd * 32 + quad * 8];
#pragma unroll
    for (int n = 0; n < 8; n++) {
      ushort8v bvv = *(const ushort8v*)&k_s[n * 16 + col16][kd * 32 + quad * 8];
      acc[n] = mfma16(av, bvv, acc[n]);
    }
  }
  __syncthreads();  // done with q_s/k_s before overwriting with sc
  const float scale = 0.08838834764831845f;  // 1/sqrt(128)
#pragma unroll
  for (int n = 0; n < 8; n++)
#pragma unroll
    for (int reg = 0; reg < 4; reg++)
      sc[w * 16 + quad * 4 + reg][n * 16 + col16] = acc[n][reg] * scale;
  __syncthreads();

  const int row = tid >> 2, p = tid & 3;
  float m = -1e30f;
  for (int c0 = 0; c0 < 32; c0++) m = fmaxf(m, sc[row][p * 32 + c0]);
  m = fmaxf(m, __shfl_xor(m, 1));
  m = fmaxf(m, __shfl_xor(m, 2));
  float s = 0.f;
  for (int c0 = 0; c0 < 32; c0++) {
    float e = __expf(sc[row][p * 32 + c0] - m);
    sc[row][p * 32 + c0] = e;
    s += e;
  }
  s += __shfl_xor(s, 1);
  s += __shfl_xor(s, 2);
  float inv = 1.f / s;
  float* orow = attn_out + ((b * 4 + h) * 128 + half * 64 + row) * 128 + p * 32;
  for (int c0 = 0; c0 < 32; c0++) orow[c0] = sc[row][p * 32 + c0] * inv;
}

// ---------------------------------------------------------------------------
// Kernel 4 (merged aolast+fuse): ao (q=127 only), last = ao@Wo^T+bo,
// collapsed GAT (2 dense layers), fusion Linear + LayerNorm + ReLU.
// grid = 16 (batch), 256 threads.
// ---------------------------------------------------------------------------
__global__ __launch_bounds__(256) void tail_kernel(
    const float* __restrict__ attn, const u16* __restrict__ Vb,
    const float* __restrict__ Wo, const float* __restrict__ bo,
    const float* __restrict__ W1, const float* __restrict__ b1,
    const float* __restrict__ g1, const float* __restrict__ be1,
    const float* __restrict__ W2, const float* __restrict__ pb2,
    const float* __restrict__ g2, const float* __restrict__ be2,
    const float* __restrict__ Wf, const float* __restrict__ bfv,
    const float* __restrict__ ln_g, const float* __restrict__ ln_b,
    float* __restrict__ dout)
{
  const int b = blockIdx.x, tid = threadIdx.x;
  __shared__ float arow[4][128];
  __shared__ float ao_s[512];
  __shared__ float last_s[512];
  __shared__ float h_s2[256];
  __shared__ float red_s[4];

  // ---- ao row (q=127) ----
#pragma unroll
  for (int e = 0; e < 2; e++) {
    int idx = tid + e * 256;
    int h = idx >> 7, k = idx & 127;
    arow[h][k] = attn[((b * 4 + h) * 128 + 127) * 128 + k];
  }
  __syncthreads();
#pragma unroll
  for (int pass = 0; pass < 2; pass++) {
    int d2 = tid + pass * 256;
    int hh = d2 >> 7;
    float acc = 0.f;
    for (int k = 0; k < 128; k++)
      acc += arow[hh][k] * b2f(Vb[(b * 128 + k) * 512 + d2]);
    ao_s[d2] = acc;
  }
  __syncthreads();
  // ---- last = ao @ Wo^T + bo ----
#pragma unroll
  for (int pass = 0; pass < 2; pass++) {
    int j = tid + pass * 256;
    float acc = bo[j];
    const float4* Wo4 = (const float4*)(Wo + j * 512);
    for (int k4 = 0; k4 < 128; k4++) {
      float4 wv = Wo4[k4];
      acc += ao_s[k4 * 4 + 0] * wv.x + ao_s[k4 * 4 + 1] * wv.y +
             ao_s[k4 * 4 + 2] * wv.z + ao_s[k4 * 4 + 3] * wv.w;
    }
    last_s[j] = acc;
  }
  __syncthreads();

  // ---- collapsed GAT layer 1 ----
  const int j = tid;
  float acc = 0.f;
  for (int k = 0; k < 512; k++) acc += last_s[k] * W1[k * 256 + j];
  float u = (acc + b1[j]) * BN_INV_F * g1[j] + be1[j];
  float h1 = u > 0.f ? u : expm1f(u);
  h_s2[j] = h1;
  __syncthreads();

  // ---- collapsed GAT layer 2 ----
  float acc2 = 0.f;
  for (int k = 0; k < 256; k++) acc2 += h_s2[k] * W2[k * 256 + j];
  float u2 = (acc2 + pb2[j]) * BN_INV_F * g2[j] + be2[j];
  float sp = u2 > 0.f ? u2 : expm1f(u2);
  __syncthreads();
  h_s2[j] = sp;
  __syncthreads();

  // ---- fusion Linear ----
  float f = bfv[j];
  const float4* Wf4 = (const float4*)(Wf + j * 768);
  for (int k4 = 0; k4 < 128; k4++) {
    float4 wv = Wf4[k4];
    f += last_s[k4 * 4 + 0] * wv.x + last_s[k4 * 4 + 1] * wv.y +
         last_s[k4 * 4 + 2] * wv.z + last_s[k4 * 4 + 3] * wv.w;
  }
  for (int k4 = 0; k4 < 64; k4++) {
    float4 wv = Wf4[128 + k4];
    f += h_s2[k4 * 4 + 0] * wv.x + h_s2[k4 * 4 + 1] * wv.y +
         h_s2[k4 * 4 + 2] * wv.z + h_s2[k4 * 4 + 3] * wv.w;
  }

  // ---- LayerNorm + ReLU ----
  float v = f;
#pragma unroll
  for (int o = 32; o > 0; o >>= 1) v += __shfl_xor(v, o);
  if ((tid & 63) == 0) red_s[tid >> 6] = v;
  __syncthreads();
  float mu = (red_s[0] + red_s[1] + red_s[2] + red_s[3]) * (1.f / 256.f);
  float dv = f - mu;
  float vv = dv * dv;
#pragma unroll
  for (int o = 32; o > 0; o >>= 1) vv += __shfl_xor(vv, o);
  __syncthreads();
  if ((tid & 63) == 0) red_s[tid >> 6] = vv;
  __syncthreads();
  float var = (red_s[0] + red_s[1] + red_s[2] + red_s[3]) * (1.f / 256.f);
  float y = dv * rsqrtf(var + 1e-5f) * ln_g[j] + ln_b[j];
  dout[b * 256 + j] = fmaxf(y, 0.f);
}

// ---------------------------------------------------------------------------
// ws layout (bytes):
//   0         hbuf  [128][2][16][256] bf16  2097152  (memset 0xFF each call)
//   2129920   tb    [16][128][512] bf16     2097152
//   4227072   Q     [2048][512] bf16        2097152
//   6324224   K     [2048][512] bf16        2097152
//   8421376   V     [2048][512] bf16        2097152  -> total 10518528 bytes
// ---------------------------------------------------------------------------
extern "C" void kernel_launch(void* const* d_in, const int* in_sizes, int n_in,
                              void* d_out, int out_size, void* d_ws, size_t ws_size,
                              hipStream_t stream) {
  (void)in_sizes; (void)n_in; (void)out_size; (void)ws_size;
  const float* x     = (const float*)d_in[0];
  const float* Wih_f = (const float*)d_in[2];
  const float* Whh_f = (const float*)d_in[3];
  const float* bih_f = (const float*)d_in[4];
  const float* bhh_f = (const float*)d_in[5];
  const float* Wih_b = (const float*)d_in[6];
  const float* Whh_b = (const float*)d_in[7];
  const float* bih_b = (const float*)d_in[8];
  const float* bhh_b = (const float*)d_in[9];
  const float* Wq = (const float*)d_in[10]; const float* bq = (const float*)d_in[11];
  const float* Wk = (const float*)d_in[12]; const float* bk = (const float*)d_in[13];
  const float* Wv = (const float*)d_in[14]; const float* bv = (const float*)d_in[15];
  const float* Wo = (const float*)d_in[16]; const float* bo = (const float*)d_in[17];
  const float* W1 = (const float*)d_in[18];
  const float* b1 = (const float*)d_in[21];
  const float* g1 = (const float*)d_in[22]; const float* be1 = (const float*)d_in[23];
  const float* W2 = (const float*)d_in[24];
  const float* pb2 = (const float*)d_in[27];
  const float* g2 = (const float*)d_in[28]; const float* be2 = (const float*)d_in[29];
  const float* Wf = (const float*)d_in[30]; const float* bfv = (const float*)d_in[31];
  const float* ln_g = (const float*)d_in[32]; const float* ln_b = (const float*)d_in[33];

  float* dout = (float*)d_out;
  char* ws = (char*)d_ws;
  u32* hbuf = (u32*)(ws + 0);
  u16* tb   = (u16*)(ws + 2129920);
  u16* Qb   = (u16*)(ws + 4227072);
  u16* Kb   = (u16*)(ws + 6324224);
  u16* Vb   = (u16*)(ws + 8421376);

  (void)hipMemsetAsync(ws, 0xFF, 2097152, stream);  // poison hbuf ring
  lstm_kernel<<<32, 256, 0, stream>>>(x, Wih_f, Whh_f, bih_f, bhh_f,
                                      Wih_b, Whh_b, bih_b, bhh_b,
                                      hbuf, tb);
  qkv_kernel<<<dim3(32, 8, 3), 256, 0, stream>>>(tb, Wq, bq, Wk, bk, Wv, bv,
                                                 Qb, Kb, Vb);
  attn_kernel<<<dim3(16, 4, 2), 256, 0, stream>>>(Qb, Kb, dout + 4096);
  tail_kernel<<<16, 256, 0, stream>>>(dout + 4096, Vb, Wo, bo,
                                      W1, b1, g1, be1, W2, pb2, g2, be2,
                                      Wf, bfv, ln_g, ln_b, dout);
}

// Round 2
// 538.967 us; speedup vs baseline: 1.1449x; 1.1449x over previous
//
#include <hip/hip_runtime.h>

// ---------------------------------------------------------------------------
// SpatioTemporalBlock: biLSTM -> temporal MHA -> (collapsed) GAT -> fusion
// B=16 S=128 F=64 H=256 HEADS=4 DH=64 AH=128 D2=512
// FP32 inputs/outputs; MFMA operands converted f32->bf16 at staging.
// GAT collapses: broadcast node features => uniform alpha => dense layers.
//
// LSTM v3 (hybrid): v1's sync fabric + v2's compute mapping.
//   - Poll/publish traffic identical to the verified 212us version:
//     WG cooperatively polls the full 8KB h(t) slab with coalesced sc1
//     dwordx4 loads (32B/thread) and stages into LDS h_s; publish via
//     relaxed agent atomic u32 stores at the same addresses.
//   - Whh/Wih fragments in registers; gate rows remapped so wave w owns
//     cols q*16+w*4..+3 x 4 gates -> i/f/g/o gathered with __shfl_xor
//     (no z_s round-trip, ONE __syncthreads per step).
//   - x-part MFMAs from direct global loads before the poll.
//   - Single-barrier safety: poll(t+1) success implies all sibling waves
//     published step t (every wave publishes), which is after their h_s
//     MFMA reads -> overwriting h_s at t+1 is safe.
// hbuf ring [128 steps][2 dir][16 b][256 c] bf16, memset 0xFF per launch;
// h never hits the NaN bit pattern (bounded by sigmoid*tanh).
// ---------------------------------------------------------------------------

typedef unsigned short u16;
typedef unsigned int u32;
typedef __bf16 bf16x8 __attribute__((ext_vector_type(8)));
typedef float f32x4 __attribute__((ext_vector_type(4)));
typedef unsigned short ushort8v __attribute__((ext_vector_type(8)));
typedef unsigned int uint4v __attribute__((ext_vector_type(4)));

#define BN_INV_F 0.9999950000374997f
#define POISON 0xFFFFFFFFu

__device__ __forceinline__ float b2f(u16 u) {
  union { float f; unsigned int i; } v;
  v.i = ((unsigned int)u) << 16;
  return v.f;
}
__device__ __forceinline__ u16 f2b(float f) {
  union { float f; unsigned int i; } v;
  v.f = f;
  unsigned int x = v.i;
  unsigned int r = (x + 0x7FFFu + ((x >> 16) & 1u)) >> 16;
  return (u16)r;
}
__device__ __forceinline__ f32x4 mfma16(ushort8v a, ushort8v b, f32x4 c) {
  return __builtin_amdgcn_mfma_f32_16x16x32_bf16(
      __builtin_bit_cast(bf16x8, a), __builtin_bit_cast(bf16x8, b), c, 0, 0, 0);
}
__device__ __forceinline__ float sigm(float x) { return 1.f / (1.f + __expf(-x)); }
__device__ __forceinline__ float tanh_f(float x) {
  float e = __expf(2.f * x);
  return 1.f - 2.f / (e + 1.f);
}

// ---------------------------------------------------------------------------
// Kernel 1: bidirectional LSTM. grid = 32 blocks: dir = bx>>4, chunk q = bx&15.
// Wave w owns h-cols q*16 + w*4 .. +3 (all 4 gates). Per lane
// (quad=ln>>4, col16=ln&15): gate row G = (col16>>2)*256 + q*16 + w*4 +
// (col16&3); Whh/Wih fragments for that row held in registers.
// Per step: x MFMAs (direct global), coalesced cooperative sc1 poll of the
// full h(t) slab -> LDS, ONE barrier, 8 Whh MFMAs (A from LDS, B from regs),
// shuffle-gather gates, gate math, publish.
// ---------------------------------------------------------------------------
__global__ __launch_bounds__(256) void lstm_kernel(
    const float* __restrict__ x,
    const float* __restrict__ Wih0, const float* __restrict__ Whh0,
    const float* __restrict__ bih0, const float* __restrict__ bhh0,
    const float* __restrict__ Wih1, const float* __restrict__ Whh1,
    const float* __restrict__ bih1, const float* __restrict__ bhh1,
    u32* __restrict__ hbuf,   // [128][2][16][128] u32 view (poisoned 0xFF)
    u16* __restrict__ tb)     // [16][128][512] bf16
{
  const int tid = threadIdx.x;
  const int bx = blockIdx.x;
  const int d = bx >> 4;
  const int q = bx & 15;
  const float* Wih = d ? Wih1 : Wih0;
  const float* Whh = d ? Whh1 : Whh0;
  const float* bih = d ? bih1 : bih0;
  const float* bhh = d ? bhh1 : bhh0;

  const int w = tid >> 6;
  const int ln = tid & 63;
  const int col16 = ln & 15;
  const int quad = ln >> 4;

  // this lane's gate row
  const int G = (col16 >> 2) * 256 + q * 16 + w * 4 + (col16 & 3);

  __shared__ u16 h_s[16][264];

  // ---- stage weights into registers (bf16 fragments) ----
  ushort8v whh_f[8];
#pragma unroll
  for (int kt = 0; kt < 8; kt++) {
    const float4* src = (const float4*)(Whh + G * 256 + kt * 32 + quad * 8);
    float4 v0 = src[0], v1 = src[1];
    ushort8v t8;
    t8[0] = f2b(v0.x); t8[1] = f2b(v0.y); t8[2] = f2b(v0.z); t8[3] = f2b(v0.w);
    t8[4] = f2b(v1.x); t8[5] = f2b(v1.y); t8[6] = f2b(v1.z); t8[7] = f2b(v1.w);
    whh_f[kt] = t8;
  }
  ushort8v wih_f[2];
#pragma unroll
  for (int kt = 0; kt < 2; kt++) {
    const float4* src = (const float4*)(Wih + G * 64 + kt * 32 + quad * 8);
    float4 v0 = src[0], v1 = src[1];
    ushort8v t8;
    t8[0] = f2b(v0.x); t8[1] = f2b(v0.y); t8[2] = f2b(v0.z); t8[3] = f2b(v0.w);
    t8[4] = f2b(v1.x); t8[5] = f2b(v1.y); t8[6] = f2b(v1.z); t8[7] = f2b(v1.w);
    wih_f[kt] = t8;
  }
  const float bias = bih[G] + bhh[G];

  f32x4 c_reg = {0.f, 0.f, 0.f, 0.f};
  const int colbase = q * 16 + w * 4 + col16;  // meaningful for col16 in {0,2}

  for (int t = 0; t < 128; t++) {
    const int pos = d ? (127 - t) : t;

    // ---- x-part: direct global loads (L1/L2-hot), f32->bf16, 2 MFMAs ----
    ushort8v ax0, ax1;
    {
      const float4* xs = (const float4*)(x + (col16 * 128 + pos) * 64 + quad * 8);
      float4 v0 = xs[0], v1 = xs[1];          // k = quad*8 .. +7
      const float4* xs1 = (const float4*)(x + (col16 * 128 + pos) * 64 + 32 + quad * 8);
      float4 v2 = xs1[0], v3 = xs1[1];        // k = 32 + quad*8 .. +7
      ax0[0] = f2b(v0.x); ax0[1] = f2b(v0.y); ax0[2] = f2b(v0.z); ax0[3] = f2b(v0.w);
      ax0[4] = f2b(v1.x); ax0[5] = f2b(v1.y); ax0[6] = f2b(v1.z); ax0[7] = f2b(v1.w);
      ax1[0] = f2b(v2.x); ax1[1] = f2b(v2.y); ax1[2] = f2b(v2.z); ax1[3] = f2b(v2.w);
      ax1[4] = f2b(v3.x); ax1[5] = f2b(v3.y); ax1[6] = f2b(v3.z); ax1[7] = f2b(v3.w);
    }
    f32x4 acc = {0.f, 0.f, 0.f, 0.f};
    acc = mfma16(ax0, wih_f[0], acc);
    acc = mfma16(ax1, wih_f[1], acc);

    if (t > 0) {
      // ---- poll full h(t): 8 u32/thread via 2 coalesced sc1 x4 loads ----
      const u32* hw = hbuf + (t * 2 + d) * 2048 + tid * 8;
      uint4v a, b;
      for (;;) {
        asm volatile(
            "global_load_dwordx4 %0, %2, off sc1\n\t"
            "global_load_dwordx4 %1, %3, off sc1\n\t"
            "s_waitcnt vmcnt(0)"
            : "=v"(a), "=v"(b)
            : "v"(hw), "v"(hw + 4)
            : "memory");
        bool ok = (a.x != POISON) & (a.y != POISON) & (a.z != POISON) &
                  (a.w != POISON) & (b.x != POISON) & (b.y != POISON) &
                  (b.z != POISON) & (b.w != POISON);
        if (ok) break;
      }
      int b_ = tid >> 4, c0 = (tid & 15) * 16;
      *(u32*)&h_s[b_][c0 + 0] = a.x;
      *(u32*)&h_s[b_][c0 + 2] = a.y;
      *(u32*)&h_s[b_][c0 + 4] = a.z;
      *(u32*)&h_s[b_][c0 + 6] = a.w;
      *(u32*)&h_s[b_][c0 + 8] = b.x;
      *(u32*)&h_s[b_][c0 + 10] = b.y;
      *(u32*)&h_s[b_][c0 + 12] = b.z;
      *(u32*)&h_s[b_][c0 + 14] = b.w;
      __syncthreads();
#pragma unroll
      for (int kt = 0; kt < 8; kt++) {
        ushort8v av = *(const ushort8v*)&h_s[col16][kt * 32 + quad * 8];
        acc = mfma16(av, whh_f[kt], acc);
      }
    }

    // ---- gather gates via shuffles (all lanes execute) ----
    float zz[4], zf[4], zg[4], zo[4];
#pragma unroll
    for (int r = 0; r < 4; r++) zz[r] = acc[r] + bias;
#pragma unroll
    for (int r = 0; r < 4; r++) {
      zf[r] = __shfl_xor(zz[r], 4);
      zg[r] = __shfl_xor(zz[r], 8);
      zo[r] = __shfl_xor(zz[r], 12);
    }

    // ---- gate math (torch order i,f,g,o); correct for col16 < 4 lanes ----
    u32 word[4];
#pragma unroll
    for (int r = 0; r < 4; r++) {
      float si = sigm(zz[r]);
      float sf = sigm(zf[r]);
      float so = sigm(zo[r]);
      float tg = tanh_f(zg[r]);
      float cc = sf * c_reg[r] + si * tg;
      c_reg[r] = cc;
      float hv = so * tanh_f(cc);
      u32 my = (u32)f2b(hv);
      u32 hi = ((u32)__shfl_xor((int)my, 1)) & 0xFFFFu;  // partner col
      word[r] = my | (hi << 16);
    }

    if (col16 == 0 || col16 == 2) {
#pragma unroll
      for (int r = 0; r < 4; r++) {
        const int batch = quad * 4 + r;
        *(u32*)&tb[(batch * 128 + pos) * 512 + d * 256 + colbase] = word[r];
        if (t < 127) {
          u32* dst = hbuf + ((t + 1) * 2 + d) * 2048 + batch * 128 + (colbase >> 1);
          __hip_atomic_store(dst, word[r], __ATOMIC_RELAXED,
                             __HIP_MEMORY_SCOPE_AGENT);
        }
      }
    }
    // no second barrier: h_s(t+1) writes are gated by poll(t+1) success,
    // which requires every sibling wave's step-t publish (after its reads).
  }
}

// ---------------------------------------------------------------------------
// Kernel 2: QKV projection.  out = t @ W^T + bias, M=2048 N=512 K=512.
// grid = (32 Mtiles, 8 Ntiles, 3 which). Q,K,V stored bf16.
// ---------------------------------------------------------------------------
__global__ __launch_bounds__(256) void qkv_kernel(
    const u16* __restrict__ tb,
    const float* __restrict__ Wq, const float* __restrict__ bq,
    const float* __restrict__ Wk, const float* __restrict__ bk,
    const float* __restrict__ Wv, const float* __restrict__ bv,
    u16* __restrict__ Qb, u16* __restrict__ Kb, u16* __restrict__ Vb)
{
  const int tid = threadIdx.x;
  const int bxm = blockIdx.x, byn = blockIdx.y, bz = blockIdx.z;
  const float* W = (bz == 0) ? Wq : ((bz == 1) ? Wk : Wv);
  const float* bias = (bz == 0) ? bq : ((bz == 1) ? bk : bv);
  u16* outp = (bz == 0) ? Qb : ((bz == 1) ? Kb : Vb);

  __shared__ u16 a_s[64][40];
  __shared__ u16 b_s[64][40];
  const int w = tid >> 6, ln = tid & 63, col16 = ln & 15, quad = ln >> 4;

  f32x4 acc[4];
#pragma unroll
  for (int n = 0; n < 4; n++) acc[n] = (f32x4){0.f, 0.f, 0.f, 0.f};

  for (int kt = 0; kt < 16; kt++) {
    int r = tid >> 2, seg = tid & 3;
    *(ushort8v*)&a_s[r][seg * 8] =
        *(const ushort8v*)(tb + (bxm * 64 + r) * 512 + kt * 32 + seg * 8);
    const float4* wsrc = (const float4*)(W + (byn * 64 + r) * 512 + kt * 32 + seg * 8);
    float4 w0 = wsrc[0], w1 = wsrc[1];
    b_s[r][seg * 8 + 0] = f2b(w0.x);
    b_s[r][seg * 8 + 1] = f2b(w0.y);
    b_s[r][seg * 8 + 2] = f2b(w0.z);
    b_s[r][seg * 8 + 3] = f2b(w0.w);
    b_s[r][seg * 8 + 4] = f2b(w1.x);
    b_s[r][seg * 8 + 5] = f2b(w1.y);
    b_s[r][seg * 8 + 6] = f2b(w1.z);
    b_s[r][seg * 8 + 7] = f2b(w1.w);
    __syncthreads();
    ushort8v av = *(const ushort8v*)&a_s[w * 16 + col16][quad * 8];
#pragma unroll
    for (int n = 0; n < 4; n++) {
      ushort8v bvv = *(const ushort8v*)&b_s[n * 16 + col16][quad * 8];
      acc[n] = mfma16(av, bvv, acc[n]);
    }
    __syncthreads();
  }
#pragma unroll
  for (int n = 0; n < 4; n++) {
    float bs = bias[byn * 64 + n * 16 + col16];
#pragma unroll
    for (int reg = 0; reg < 4; reg++) {
      int row = bxm * 64 + w * 16 + quad * 4 + reg;
      outp[row * 512 + byn * 64 + n * 16 + col16] = f2b(acc[n][reg] + bs);
    }
  }
}

// ---------------------------------------------------------------------------
// Kernel 3: scores + softmax -> attn (d_out, f32). grid = (16 b, 4 h, 2 qhalf).
// Epilogue: per-row inv staged in LDS, cooperative coalesced float4 stores.
// ---------------------------------------------------------------------------
__global__ __launch_bounds__(256) void attn_kernel(
    const u16* __restrict__ Qb, const u16* __restrict__ Kb,
    float* __restrict__ attn_out)
{
  const int b = blockIdx.x, h = blockIdx.y, half = blockIdx.z;
  const int tid = threadIdx.x;
  __shared__ __align__(16) char smem[52224];
  __shared__ float inv_s[64];
  u16 (*q_s)[136] = (u16(*)[136])smem;
  u16 (*k_s)[136] = (u16(*)[136])(smem + 17408);
  float (*sc)[132] = (float(*)[132])smem;  // reused after MFMA

  const int w = tid >> 6, ln = tid & 63, col16 = ln & 15, quad = ln >> 4;
  {
    int r = tid >> 2, seg = tid & 3;
    const u16* src = Qb + (b * 128 + half * 64 + r) * 512 + h * 128 + seg * 32;
#pragma unroll
    for (int i = 0; i < 4; i++)
      *(ushort8v*)&q_s[r][seg * 32 + i * 8] = *(const ushort8v*)(src + i * 8);
    int r2 = tid >> 1, sg = tid & 1;
    const u16* src2 = Kb + (b * 128 + r2) * 512 + h * 128 + sg * 64;
#pragma unroll
    for (int i = 0; i < 8; i++)
      *(ushort8v*)&k_s[r2][sg * 64 + i * 8] = *(const ushort8v*)(src2 + i * 8);
  }
  __syncthreads();

  f32x4 acc[8];
#pragma unroll
  for (int n = 0; n < 8; n++) acc[n] = (f32x4){0.f, 0.f, 0.f, 0.f};
#pragma unroll
  for (int kd = 0; kd < 4; kd++) {
    ushort8v av = *(const ushort8v*)&q_s[w * 16 + col16][kd * 32 + quad * 8];
#pragma unroll
    for (int n = 0; n < 8; n++) {
      ushort8v bvv = *(const ushort8v*)&k_s[n * 16 + col16][kd * 32 + quad * 8];
      acc[n] = mfma16(av, bvv, acc[n]);
    }
  }
  __syncthreads();  // done with q_s/k_s before overwriting with sc
  const float scale = 0.08838834764831845f;  // 1/sqrt(128)
#pragma unroll
  for (int n = 0; n < 8; n++)
#pragma unroll
    for (int reg = 0; reg < 4; reg++)
      sc[w * 16 + quad * 4 + reg][n * 16 + col16] = acc[n][reg] * scale;
  __syncthreads();

  const int row = tid >> 2, p = tid & 3;
  float m = -1e30f;
  for (int c0 = 0; c0 < 32; c0++) m = fmaxf(m, sc[row][p * 32 + c0]);
  m = fmaxf(m, __shfl_xor(m, 1));
  m = fmaxf(m, __shfl_xor(m, 2));
  float s = 0.f;
  for (int c0 = 0; c0 < 32; c0++) {
    float e = __expf(sc[row][p * 32 + c0] - m);
    sc[row][p * 32 + c0] = e;
    s += e;
  }
  s += __shfl_xor(s, 1);
  s += __shfl_xor(s, 2);
  if (p == 0) inv_s[row] = 1.f / s;
  __syncthreads();

  // cooperative coalesced store: 64 rows x 128 f32
  float* obase = attn_out + (size_t)((b * 4 + h) * 128 + half * 64) * 128;
#pragma unroll
  for (int it = 0; it < 8; it++) {
    int idx = tid + it * 256;     // 0..2047
    int r = idx >> 5;             // row 0..63
    int c4 = idx & 31;            // float4 index 0..31
    float4 ev = *(float4*)&sc[r][c4 * 4];
    float iv = inv_s[r];
    float4 ov = {ev.x * iv, ev.y * iv, ev.z * iv, ev.w * iv};
    *(float4*)&obase[r * 128 + c4 * 4] = ov;
  }
}

// ---------------------------------------------------------------------------
// Kernel 4 (merged aolast+fuse): ao (q=127 only), last = ao@Wo^T+bo,
// collapsed GAT (2 dense layers), fusion Linear + LayerNorm + ReLU.
// grid = 16 (batch), 256 threads.
// ---------------------------------------------------------------------------
__global__ __launch_bounds__(256) void tail_kernel(
    const float* __restrict__ attn, const u16* __restrict__ Vb,
    const float* __restrict__ Wo, const float* __restrict__ bo,
    const float* __restrict__ W1, const float* __restrict__ b1,
    const float* __restrict__ g1, const float* __restrict__ be1,
    const float* __restrict__ W2, const float* __restrict__ pb2,
    const float* __restrict__ g2, const float* __restrict__ be2,
    const float* __restrict__ Wf, const float* __restrict__ bfv,
    const float* __restrict__ ln_g, const float* __restrict__ ln_b,
    float* __restrict__ dout)
{
  const int b = blockIdx.x, tid = threadIdx.x;
  __shared__ float arow[4][128];
  __shared__ float ao_s[512];
  __shared__ float last_s[512];
  __shared__ float h_s2[256];
  __shared__ float red_s[4];

  // ---- ao row (q=127) ----
#pragma unroll
  for (int e = 0; e < 2; e++) {
    int idx = tid + e * 256;
    int h = idx >> 7, k = idx & 127;
    arow[h][k] = attn[((b * 4 + h) * 128 + 127) * 128 + k];
  }
  __syncthreads();
#pragma unroll
  for (int pass = 0; pass < 2; pass++) {
    int d2 = tid + pass * 256;
    int hh = d2 >> 7;
    float acc = 0.f;
    for (int k = 0; k < 128; k++)
      acc += arow[hh][k] * b2f(Vb[(b * 128 + k) * 512 + d2]);
    ao_s[d2] = acc;
  }
  __syncthreads();
  // ---- last = ao @ Wo^T + bo ----
#pragma unroll
  for (int pass = 0; pass < 2; pass++) {
    int j = tid + pass * 256;
    float acc = bo[j];
    const float4* Wo4 = (const float4*)(Wo + j * 512);
    for (int k4 = 0; k4 < 128; k4++) {
      float4 wv = Wo4[k4];
      acc += ao_s[k4 * 4 + 0] * wv.x + ao_s[k4 * 4 + 1] * wv.y +
             ao_s[k4 * 4 + 2] * wv.z + ao_s[k4 * 4 + 3] * wv.w;
    }
    last_s[j] = acc;
  }
  __syncthreads();

  // ---- collapsed GAT layer 1 ----
  const int j = tid;
  float acc = 0.f;
  for (int k = 0; k < 512; k++) acc += last_s[k] * W1[k * 256 + j];
  float u = (acc + b1[j]) * BN_INV_F * g1[j] + be1[j];
  float h1 = u > 0.f ? u : expm1f(u);
  h_s2[j] = h1;
  __syncthreads();

  // ---- collapsed GAT layer 2 ----
  float acc2 = 0.f;
  for (int k = 0; k < 256; k++) acc2 += h_s2[k] * W2[k * 256 + j];
  float u2 = (acc2 + pb2[j]) * BN_INV_F * g2[j] + be2[j];
  float sp = u2 > 0.f ? u2 : expm1f(u2);
  __syncthreads();
  h_s2[j] = sp;
  __syncthreads();

  // ---- fusion Linear ----
  float f = bfv[j];
  const float4* Wf4 = (const float4*)(Wf + j * 768);
  for (int k4 = 0; k4 < 128; k4++) {
    float4 wv = Wf4[k4];
    f += last_s[k4 * 4 + 0] * wv.x + last_s[k4 * 4 + 1] * wv.y +
         last_s[k4 * 4 + 2] * wv.z + last_s[k4 * 4 + 3] * wv.w;
  }
  for (int k4 = 0; k4 < 64; k4++) {
    float4 wv = Wf4[128 + k4];
    f += h_s2[k4 * 4 + 0] * wv.x + h_s2[k4 * 4 + 1] * wv.y +
         h_s2[k4 * 4 + 2] * wv.z + h_s2[k4 * 4 + 3] * wv.w;
  }

  // ---- LayerNorm + ReLU ----
  float v = f;
#pragma unroll
  for (int o = 32; o > 0; o >>= 1) v += __shfl_xor(v, o);
  if ((tid & 63) == 0) red_s[tid >> 6] = v;
  __syncthreads();
  float mu = (red_s[0] + red_s[1] + red_s[2] + red_s[3]) * (1.f / 256.f);
  float dv = f - mu;
  float vv = dv * dv;
#pragma unroll
  for (int o = 32; o > 0; o >>= 1) vv += __shfl_xor(vv, o);
  __syncthreads();
  if ((tid & 63) == 0) red_s[tid >> 6] = vv;
  __syncthreads();
  float var = (red_s[0] + red_s[1] + red_s[2] + red_s[3]) * (1.f / 256.f);
  float y = dv * rsqrtf(var + 1e-5f) * ln_g[j] + ln_b[j];
  dout[b * 256 + j] = fmaxf(y, 0.f);
}

// ---------------------------------------------------------------------------
// ws layout (bytes):
//   0         hbuf  [128][2][16][256] bf16  2097152  (memset 0xFF each call)
//   2129920   tb    [16][128][512] bf16     2097152
//   4227072   Q     [2048][512] bf16        2097152
//   6324224   K     [2048][512] bf16        2097152
//   8421376   V     [2048][512] bf16        2097152  -> total 10518528 bytes
// ---------------------------------------------------------------------------
extern "C" void kernel_launch(void* const* d_in, const int* in_sizes, int n_in,
                              void* d_out, int out_size, void* d_ws, size_t ws_size,
                              hipStream_t stream) {
  (void)in_sizes; (void)n_in; (void)out_size; (void)ws_size;
  const float* x     = (const float*)d_in[0];
  const float* Wih_f = (const float*)d_in[2];
  const float* Whh_f = (const float*)d_in[3];
  const float* bih_f = (const float*)d_in[4];
  const float* bhh_f = (const float*)d_in[5];
  const float* Wih_b = (const float*)d_in[6];
  const float* Whh_b = (const float*)d_in[7];
  const float* bih_b = (const float*)d_in[8];
  const float* bhh_b = (const float*)d_in[9];
  const float* Wq = (const float*)d_in[10]; const float* bq = (const float*)d_in[11];
  const float* Wk = (const float*)d_in[12]; const float* bk = (const float*)d_in[13];
  const float* Wv = (const float*)d_in[14]; const float* bv = (const float*)d_in[15];
  const float* Wo = (const float*)d_in[16]; const float* bo = (const float*)d_in[17];
  const float* W1 = (const float*)d_in[18];
  const float* b1 = (const float*)d_in[21];
  const float* g1 = (const float*)d_in[22]; const float* be1 = (const float*)d_in[23];
  const float* W2 = (const float*)d_in[24];
  const float* pb2 = (const float*)d_in[27];
  const float* g2 = (const float*)d_in[28]; const float* be2 = (const float*)d_in[29];
  const float* Wf = (const float*)d_in[30]; const float* bfv = (const float*)d_in[31];
  const float* ln_g = (const float*)d_in[32]; const float* ln_b = (const float*)d_in[33];

  float* dout = (float*)d_out;
  char* ws = (char*)d_ws;
  u32* hbuf = (u32*)(ws + 0);
  u16* tb   = (u16*)(ws + 2129920);
  u16* Qb   = (u16*)(ws + 4227072);
  u16* Kb   = (u16*)(ws + 6324224);
  u16* Vb   = (u16*)(ws + 8421376);

  (void)hipMemsetAsync(ws, 0xFF, 2097152, stream);  // poison hbuf ring
  lstm_kernel<<<32, 256, 0, stream>>>(x, Wih_f, Whh_f, bih_f, bhh_f,
                                      Wih_b, Whh_b, bih_b, bhh_b,
                                      hbuf, tb);
  qkv_kernel<<<dim3(32, 8, 3), 256, 0, stream>>>(tb, Wq, bq, Wk, bk, Wv, bv,
                                                 Qb, Kb, Vb);
  attn_kernel<<<dim3(16, 4, 2), 256, 0, stream>>>(Qb, Kb, dout + 4096);
  tail_kernel<<<16, 256, 0, stream>>>(dout + 4096, Vb, Wo, bo,
                                      W1, b1, g1, be1, W2, pb2, g2, be2,
                                      Wf, bfv, ln_g, ln_b, dout);
}

// Round 3
// 521.462 us; speedup vs baseline: 1.1833x; 1.0336x over previous
//
#include <hip/hip_runtime.h>

// ---------------------------------------------------------------------------
// SpatioTemporalBlock: biLSTM -> temporal MHA -> (collapsed) GAT -> fusion
// B=16 S=128 F=64 H=256 HEADS=4 DH=64 AH=128 D2=512
// FP32 inputs/outputs; MFMA operands converted f32->bf16 at staging.
// GAT collapses: broadcast node features => uniform alpha => dense layers.
//
// LSTM v4: v3's register-weight compute + v1's EXACT coalesced publish.
//   - Poll: WG cooperatively polls the full 8KB h(t) slab with coalesced
//     sc1 dwordx4 loads (32B/thread) and stages into LDS h_s (v1 fabric).
//   - Compute: Whh/Wih fragments in registers; wave w owns cols q*16+w*4..+3
//     x 4 gates; i/f/g/o gathered with __shfl_xor; x-part MFMAs from direct
//     global loads issued before the poll.
//   - Publish: h staged through a 512B LDS buffer, then re-emitted with v1's
//     tid->address mapping (thread eb=tid>>4, ec=tid&15, even ec stores one
//     u32 at eb*128+(q*16+ec)/2): 32B-contiguous per batch => no write
//     amplification (v2/v3's scattered publish cost ~2.5x WRITE_SIZE and
//     ~100us of visibility latency).
// hbuf ring [128 steps][2 dir][16 b][256 c] bf16, memset 0xFF per launch;
// h never hits the NaN bit pattern (bounded by sigmoid*tanh).
// ---------------------------------------------------------------------------

typedef unsigned short u16;
typedef unsigned int u32;
typedef __bf16 bf16x8 __attribute__((ext_vector_type(8)));
typedef float f32x4 __attribute__((ext_vector_type(4)));
typedef unsigned short ushort8v __attribute__((ext_vector_type(8)));
typedef unsigned int uint4v __attribute__((ext_vector_type(4)));

#define BN_INV_F 0.9999950000374997f
#define POISON 0xFFFFFFFFu

__device__ __forceinline__ float b2f(u16 u) {
  union { float f; unsigned int i; } v;
  v.i = ((unsigned int)u) << 16;
  return v.f;
}
__device__ __forceinline__ u16 f2b(float f) {
  union { float f; unsigned int i; } v;
  v.f = f;
  unsigned int x = v.i;
  unsigned int r = (x + 0x7FFFu + ((x >> 16) & 1u)) >> 16;
  return (u16)r;
}
__device__ __forceinline__ f32x4 mfma16(ushort8v a, ushort8v b, f32x4 c) {
  return __builtin_amdgcn_mfma_f32_16x16x32_bf16(
      __builtin_bit_cast(bf16x8, a), __builtin_bit_cast(bf16x8, b), c, 0, 0, 0);
}
__device__ __forceinline__ float sigm(float x) { return 1.f / (1.f + __expf(-x)); }
__device__ __forceinline__ float tanh_f(float x) {
  float e = __expf(2.f * x);
  return 1.f - 2.f / (e + 1.f);
}

// ---------------------------------------------------------------------------
// Kernel 1: bidirectional LSTM. grid = 32 blocks: dir = bx>>4, chunk q = bx&15.
// Wave w owns h-cols q*16 + w*4 .. +3 (all 4 gates). Per lane
// (quad=ln>>4, col16=ln&15): gate row G = (col16>>2)*256 + q*16 + w*4 +
// (col16&3); Whh/Wih fragments for that row held in registers.
// Per step: x MFMAs (direct global), coalesced cooperative sc1 poll of the
// full h(t) slab -> LDS, barrier, 8 Whh MFMAs (A from LDS, B from regs),
// shuffle-gather gates, gate math (true h in lanes col16<4), stage h chunk
// to LDS, barrier, v1-style coalesced publish.
// ---------------------------------------------------------------------------
__global__ __launch_bounds__(256) void lstm_kernel(
    const float* __restrict__ x,
    const float* __restrict__ Wih0, const float* __restrict__ Whh0,
    const float* __restrict__ bih0, const float* __restrict__ bhh0,
    const float* __restrict__ Wih1, const float* __restrict__ Whh1,
    const float* __restrict__ bih1, const float* __restrict__ bhh1,
    u32* __restrict__ hbuf,   // [128][2][16][128] u32 view (poisoned 0xFF)
    u16* __restrict__ tb)     // [16][128][512] bf16
{
  const int tid = threadIdx.x;
  const int bx = blockIdx.x;
  const int d = bx >> 4;
  const int q = bx & 15;
  const float* Wih = d ? Wih1 : Wih0;
  const float* Whh = d ? Whh1 : Whh0;
  const float* bih = d ? bih1 : bih0;
  const float* bhh = d ? bhh1 : bhh0;

  const int w = tid >> 6;
  const int ln = tid & 63;
  const int col16 = ln & 15;
  const int quad = ln >> 4;

  // this lane's gate row
  const int G = (col16 >> 2) * 256 + q * 16 + w * 4 + (col16 & 3);

  __shared__ u16 h_s[16][264];
  __shared__ u16 hout_s[16][18];   // h chunk staging for coalesced publish

  // ---- stage weights into registers (bf16 fragments) ----
  ushort8v whh_f[8];
#pragma unroll
  for (int kt = 0; kt < 8; kt++) {
    const float4* src = (const float4*)(Whh + G * 256 + kt * 32 + quad * 8);
    float4 v0 = src[0], v1 = src[1];
    ushort8v t8;
    t8[0] = f2b(v0.x); t8[1] = f2b(v0.y); t8[2] = f2b(v0.z); t8[3] = f2b(v0.w);
    t8[4] = f2b(v1.x); t8[5] = f2b(v1.y); t8[6] = f2b(v1.z); t8[7] = f2b(v1.w);
    whh_f[kt] = t8;
  }
  ushort8v wih_f[2];
#pragma unroll
  for (int kt = 0; kt < 2; kt++) {
    const float4* src = (const float4*)(Wih + G * 64 + kt * 32 + quad * 8);
    float4 v0 = src[0], v1 = src[1];
    ushort8v t8;
    t8[0] = f2b(v0.x); t8[1] = f2b(v0.y); t8[2] = f2b(v0.z); t8[3] = f2b(v0.w);
    t8[4] = f2b(v1.x); t8[5] = f2b(v1.y); t8[6] = f2b(v1.z); t8[7] = f2b(v1.w);
    wih_f[kt] = t8;
  }
  const float bias = bih[G] + bhh[G];

  f32x4 c_reg = {0.f, 0.f, 0.f, 0.f};

  for (int t = 0; t < 128; t++) {
    const int pos = d ? (127 - t) : t;

    // ---- x-part: direct global loads (L1/L2-hot), f32->bf16, 2 MFMAs ----
    ushort8v ax0, ax1;
    {
      const float4* xs = (const float4*)(x + (col16 * 128 + pos) * 64 + quad * 8);
      float4 v0 = xs[0], v1 = xs[1];          // k = quad*8 .. +7
      const float4* xs1 = (const float4*)(x + (col16 * 128 + pos) * 64 + 32 + quad * 8);
      float4 v2 = xs1[0], v3 = xs1[1];        // k = 32 + quad*8 .. +7
      ax0[0] = f2b(v0.x); ax0[1] = f2b(v0.y); ax0[2] = f2b(v0.z); ax0[3] = f2b(v0.w);
      ax0[4] = f2b(v1.x); ax0[5] = f2b(v1.y); ax0[6] = f2b(v1.z); ax0[7] = f2b(v1.w);
      ax1[0] = f2b(v2.x); ax1[1] = f2b(v2.y); ax1[2] = f2b(v2.z); ax1[3] = f2b(v2.w);
      ax1[4] = f2b(v3.x); ax1[5] = f2b(v3.y); ax1[6] = f2b(v3.z); ax1[7] = f2b(v3.w);
    }
    f32x4 acc = {0.f, 0.f, 0.f, 0.f};
    acc = mfma16(ax0, wih_f[0], acc);
    acc = mfma16(ax1, wih_f[1], acc);

    if (t > 0) {
      // ---- poll full h(t): 8 u32/thread via 2 coalesced sc1 x4 loads ----
      const u32* hw = hbuf + (t * 2 + d) * 2048 + tid * 8;
      uint4v a, b;
      for (;;) {
        asm volatile(
            "global_load_dwordx4 %0, %2, off sc1\n\t"
            "global_load_dwordx4 %1, %3, off sc1\n\t"
            "s_waitcnt vmcnt(0)"
            : "=v"(a), "=v"(b)
            : "v"(hw), "v"(hw + 4)
            : "memory");
        bool ok = (a.x != POISON) & (a.y != POISON) & (a.z != POISON) &
                  (a.w != POISON) & (b.x != POISON) & (b.y != POISON) &
                  (b.z != POISON) & (b.w != POISON);
        if (ok) break;
      }
      int b_ = tid >> 4, c0 = (tid & 15) * 16;
      *(u32*)&h_s[b_][c0 + 0] = a.x;
      *(u32*)&h_s[b_][c0 + 2] = a.y;
      *(u32*)&h_s[b_][c0 + 4] = a.z;
      *(u32*)&h_s[b_][c0 + 6] = a.w;
      *(u32*)&h_s[b_][c0 + 8] = b.x;
      *(u32*)&h_s[b_][c0 + 10] = b.y;
      *(u32*)&h_s[b_][c0 + 12] = b.z;
      *(u32*)&h_s[b_][c0 + 14] = b.w;
      __syncthreads();
#pragma unroll
      for (int kt = 0; kt < 8; kt++) {
        ushort8v av = *(const ushort8v*)&h_s[col16][kt * 32 + quad * 8];
        acc = mfma16(av, whh_f[kt], acc);
      }
    }

    // ---- gather gates via shuffles (all lanes execute) ----
    float zz[4], zf[4], zg[4], zo[4];
#pragma unroll
    for (int r = 0; r < 4; r++) zz[r] = acc[r] + bias;
#pragma unroll
    for (int r = 0; r < 4; r++) {
      zf[r] = __shfl_xor(zz[r], 4);
      zg[r] = __shfl_xor(zz[r], 8);
      zo[r] = __shfl_xor(zz[r], 12);
    }

    // ---- gate math (torch order i,f,g,o); true h in lanes col16 < 4 ----
    float hvs[4];
#pragma unroll
    for (int r = 0; r < 4; r++) {
      float si = sigm(zz[r]);
      float sf = sigm(zf[r]);
      float so = sigm(zo[r]);
      float tg = tanh_f(zg[r]);
      float cc = sf * c_reg[r] + si * tg;
      c_reg[r] = cc;
      hvs[r] = so * tanh_f(cc);
    }

    // ---- stage h chunk to LDS (owners: col16 < 4) ----
    if (col16 < 4) {
#pragma unroll
      for (int r = 0; r < 4; r++)
        hout_s[quad * 4 + r][w * 4 + col16] = f2b(hvs[r]);
    }
    __syncthreads();

    // ---- v1-style coalesced publish: 32B contiguous per batch ----
    {
      const int eb = tid >> 4, ec = tid & 15;
      if ((ec & 1) == 0) {
        u32 word = (u32)hout_s[eb][ec] | ((u32)hout_s[eb][ec + 1] << 16);
        *(u32*)&tb[(eb * 128 + pos) * 512 + d * 256 + q * 16 + ec] = word;
        if (t < 127) {
          u32* dst = hbuf + ((t + 1) * 2 + d) * 2048 + eb * 128 + ((q * 16 + ec) >> 1);
          __hip_atomic_store(dst, word, __ATOMIC_RELAXED,
                             __HIP_MEMORY_SCOPE_AGENT);
        }
      }
    }
    // no third barrier: h_s/hout_s writes at t+1 are gated by poll(t+1)
    // success, which requires THIS WG's own publish of slab t+1 (end of
    // step t) to be visible -> all threads passed the bar2 above -> all
    // step-t LDS reads completed.
  }
}

// ---------------------------------------------------------------------------
// Kernel 2: QKV projection.  out = t @ W^T + bias, M=2048 N=512 K=512.
// grid = (32 Mtiles, 8 Ntiles, 3 which). Q,K,V stored bf16.
// ---------------------------------------------------------------------------
__global__ __launch_bounds__(256) void qkv_kernel(
    const u16* __restrict__ tb,
    const float* __restrict__ Wq, const float* __restrict__ bq,
    const float* __restrict__ Wk, const float* __restrict__ bk,
    const float* __restrict__ Wv, const float* __restrict__ bv,
    u16* __restrict__ Qb, u16* __restrict__ Kb, u16* __restrict__ Vb)
{
  const int tid = threadIdx.x;
  const int bxm = blockIdx.x, byn = blockIdx.y, bz = blockIdx.z;
  const float* W = (bz == 0) ? Wq : ((bz == 1) ? Wk : Wv);
  const float* bias = (bz == 0) ? bq : ((bz == 1) ? bk : bv);
  u16* outp = (bz == 0) ? Qb : ((bz == 1) ? Kb : Vb);

  __shared__ u16 a_s[64][40];
  __shared__ u16 b_s[64][40];
  const int w = tid >> 6, ln = tid & 63, col16 = ln & 15, quad = ln >> 4;

  f32x4 acc[4];
#pragma unroll
  for (int n = 0; n < 4; n++) acc[n] = (f32x4){0.f, 0.f, 0.f, 0.f};

  for (int kt = 0; kt < 16; kt++) {
    int r = tid >> 2, seg = tid & 3;
    *(ushort8v*)&a_s[r][seg * 8] =
        *(const ushort8v*)(tb + (bxm * 64 + r) * 512 + kt * 32 + seg * 8);
    const float4* wsrc = (const float4*)(W + (byn * 64 + r) * 512 + kt * 32 + seg * 8);
    float4 w0 = wsrc[0], w1 = wsrc[1];
    b_s[r][seg * 8 + 0] = f2b(w0.x);
    b_s[r][seg * 8 + 1] = f2b(w0.y);
    b_s[r][seg * 8 + 2] = f2b(w0.z);
    b_s[r][seg * 8 + 3] = f2b(w0.w);
    b_s[r][seg * 8 + 4] = f2b(w1.x);
    b_s[r][seg * 8 + 5] = f2b(w1.y);
    b_s[r][seg * 8 + 6] = f2b(w1.z);
    b_s[r][seg * 8 + 7] = f2b(w1.w);
    __syncthreads();
    ushort8v av = *(const ushort8v*)&a_s[w * 16 + col16][quad * 8];
#pragma unroll
    for (int n = 0; n < 4; n++) {
      ushort8v bvv = *(const ushort8v*)&b_s[n * 16 + col16][quad * 8];
      acc[n] = mfma16(av, bvv, acc[n]);
    }
    __syncthreads();
  }
#pragma unroll
  for (int n = 0; n < 4; n++) {
    float bs = bias[byn * 64 + n * 16 + col16];
#pragma unroll
    for (int reg = 0; reg < 4; reg++) {
      int row = bxm * 64 + w * 16 + quad * 4 + reg;
      outp[row * 512 + byn * 64 + n * 16 + col16] = f2b(acc[n][reg] + bs);
    }
  }
}

// ---------------------------------------------------------------------------
// Kernel 3: scores + softmax -> attn (d_out, f32). grid = (16 b, 4 h, 2 qhalf).
// Epilogue: per-row inv staged in LDS, cooperative coalesced float4 stores.
// ---------------------------------------------------------------------------
__global__ __launch_bounds__(256) void attn_kernel(
    const u16* __restrict__ Qb, const u16* __restrict__ Kb,
    float* __restrict__ attn_out)
{
  const int b = blockIdx.x, h = blockIdx.y, half = blockIdx.z;
  const int tid = threadIdx.x;
  __shared__ __align__(16) char smem[52224];
  __shared__ float inv_s[64];
  u16 (*q_s)[136] = (u16(*)[136])smem;
  u16 (*k_s)[136] = (u16(*)[136])(smem + 17408);
  float (*sc)[132] = (float(*)[132])smem;  // reused after MFMA

  const int w = tid >> 6, ln = tid & 63, col16 = ln & 15, quad = ln >> 4;
  {
    int r = tid >> 2, seg = tid & 3;
    const u16* src = Qb + (b * 128 + half * 64 + r) * 512 + h * 128 + seg * 32;
#pragma unroll
    for (int i = 0; i < 4; i++)
      *(ushort8v*)&q_s[r][seg * 32 + i * 8] = *(const ushort8v*)(src + i * 8);
    int r2 = tid >> 1, sg = tid & 1;
    const u16* src2 = Kb + (b * 128 + r2) * 512 + h * 128 + sg * 64;
#pragma unroll
    for (int i = 0; i < 8; i++)
      *(ushort8v*)&k_s[r2][sg * 64 + i * 8] = *(const ushort8v*)(src2 + i * 8);
  }
  __syncthreads();

  f32x4 acc[8];
#pragma unroll
  for (int n = 0; n < 8; n++) acc[n] = (f32x4){0.f, 0.f, 0.f, 0.f};
#pragma unroll
  for (int kd = 0; kd < 4; kd++) {
    ushort8v av = *(const ushort8v*)&q_s[w * 16 + col16][kd * 32 + quad * 8];
#pragma unroll
    for (int n = 0; n < 8; n++) {
      ushort8v bvv = *(const ushort8v*)&k_s[n * 16 + col16][kd * 32 + quad * 8];
      acc[n] = mfma16(av, bvv, acc[n]);
    }
  }
  __syncthreads();  // done with q_s/k_s before overwriting with sc
  const float scale = 0.08838834764831845f;  // 1/sqrt(128)
#pragma unroll
  for (int n = 0; n < 8; n++)
#pragma unroll
    for (int reg = 0; reg < 4; reg++)
      sc[w * 16 + quad * 4 + reg][n * 16 + col16] = acc[n][reg] * scale;
  __syncthreads();

  const int row = tid >> 2, p = tid & 3;
  float m = -1e30f;
  for (int c0 = 0; c0 < 32; c0++) m = fmaxf(m, sc[row][p * 32 + c0]);
  m = fmaxf(m, __shfl_xor(m, 1));
  m = fmaxf(m, __shfl_xor(m, 2));
  float s = 0.f;
  for (int c0 = 0; c0 < 32; c0++) {
    float e = __expf(sc[row][p * 32 + c0] - m);
    sc[row][p * 32 + c0] = e;
    s += e;
  }
  s += __shfl_xor(s, 1);
  s += __shfl_xor(s, 2);
  if (p == 0) inv_s[row] = 1.f / s;
  __syncthreads();

  // cooperative coalesced store: 64 rows x 128 f32
  float* obase = attn_out + (size_t)((b * 4 + h) * 128 + half * 64) * 128;
#pragma unroll
  for (int it = 0; it < 8; it++) {
    int idx = tid + it * 256;     // 0..2047
    int r = idx >> 5;             // row 0..63
    int c4 = idx & 31;            // float4 index 0..31
    float4 ev = *(float4*)&sc[r][c4 * 4];
    float iv = inv_s[r];
    float4 ov = {ev.x * iv, ev.y * iv, ev.z * iv, ev.w * iv};
    *(float4*)&obase[r * 128 + c4 * 4] = ov;
  }
}

// ---------------------------------------------------------------------------
// Kernel 4 (merged aolast+fuse): ao (q=127 only), last = ao@Wo^T+bo,
// collapsed GAT (2 dense layers), fusion Linear + LayerNorm + ReLU.
// grid = 16 (batch), 256 threads.
// ---------------------------------------------------------------------------
__global__ __launch_bounds__(256) void tail_kernel(
    const float* __restrict__ attn, const u16* __restrict__ Vb,
    const float* __restrict__ Wo, const float* __restrict__ bo,
    const float* __restrict__ W1, const float* __restrict__ b1,
    const float* __restrict__ g1, const float* __restrict__ be1,
    const float* __restrict__ W2, const float* __restrict__ pb2,
    const float* __restrict__ g2, const float* __restrict__ be2,
    const float* __restrict__ Wf, const float* __restrict__ bfv,
    const float* __restrict__ ln_g, const float* __restrict__ ln_b,
    float* __restrict__ dout)
{
  const int b = blockIdx.x, tid = threadIdx.x;
  __shared__ float arow[4][128];
  __shared__ float ao_s[512];
  __shared__ float last_s[512];
  __shared__ float h_s2[256];
  __shared__ float red_s[4];

  // ---- ao row (q=127) ----
#pragma unroll
  for (int e = 0; e < 2; e++) {
    int idx = tid + e * 256;
    int h = idx >> 7, k = idx & 127;
    arow[h][k] = attn[((b * 4 + h) * 128 + 127) * 128 + k];
  }
  __syncthreads();
#pragma unroll
  for (int pass = 0; pass < 2; pass++) {
    int d2 = tid + pass * 256;
    int hh = d2 >> 7;
    float acc = 0.f;
    for (int k = 0; k < 128; k++)
      acc += arow[hh][k] * b2f(Vb[(b * 128 + k) * 512 + d2]);
    ao_s[d2] = acc;
  }
  __syncthreads();
  // ---- last = ao @ Wo^T + bo ----
#pragma unroll
  for (int pass = 0; pass < 2; pass++) {
    int j = tid + pass * 256;
    float acc = bo[j];
    const float4* Wo4 = (const float4*)(Wo + j * 512);
    for (int k4 = 0; k4 < 128; k4++) {
      float4 wv = Wo4[k4];
      acc += ao_s[k4 * 4 + 0] * wv.x + ao_s[k4 * 4 + 1] * wv.y +
             ao_s[k4 * 4 + 2] * wv.z + ao_s[k4 * 4 + 3] * wv.w;
    }
    last_s[j] = acc;
  }
  __syncthreads();

  // ---- collapsed GAT layer 1 ----
  const int j = tid;
  float acc = 0.f;
  for (int k = 0; k < 512; k++) acc += last_s[k] * W1[k * 256 + j];
  float u = (acc + b1[j]) * BN_INV_F * g1[j] + be1[j];
  float h1 = u > 0.f ? u : expm1f(u);
  h_s2[j] = h1;
  __syncthreads();

  // ---- collapsed GAT layer 2 ----
  float acc2 = 0.f;
  for (int k = 0; k < 256; k++) acc2 += h_s2[k] * W2[k * 256 + j];
  float u2 = (acc2 + pb2[j]) * BN_INV_F * g2[j] + be2[j];
  float sp = u2 > 0.f ? u2 : expm1f(u2);
  __syncthreads();
  h_s2[j] = sp;
  __syncthreads();

  // ---- fusion Linear ----
  float f = bfv[j];
  const float4* Wf4 = (const float4*)(Wf + j * 768);
  for (int k4 = 0; k4 < 128; k4++) {
    float4 wv = Wf4[k4];
    f += last_s[k4 * 4 + 0] * wv.x + last_s[k4 * 4 + 1] * wv.y +
         last_s[k4 * 4 + 2] * wv.z + last_s[k4 * 4 + 3] * wv.w;
  }
  for (int k4 = 0; k4 < 64; k4++) {
    float4 wv = Wf4[128 + k4];
    f += h_s2[k4 * 4 + 0] * wv.x + h_s2[k4 * 4 + 1] * wv.y +
         h_s2[k4 * 4 + 2] * wv.z + h_s2[k4 * 4 + 3] * wv.w;
  }

  // ---- LayerNorm + ReLU ----
  float v = f;
#pragma unroll
  for (int o = 32; o > 0; o >>= 1) v += __shfl_xor(v, o);
  if ((tid & 63) == 0) red_s[tid >> 6] = v;
  __syncthreads();
  float mu = (red_s[0] + red_s[1] + red_s[2] + red_s[3]) * (1.f / 256.f);
  float dv = f - mu;
  float vv = dv * dv;
#pragma unroll
  for (int o = 32; o > 0; o >>= 1) vv += __shfl_xor(vv, o);
  __syncthreads();
  if ((tid & 63) == 0) red_s[tid >> 6] = vv;
  __syncthreads();
  float var = (red_s[0] + red_s[1] + red_s[2] + red_s[3]) * (1.f / 256.f);
  float y = dv * rsqrtf(var + 1e-5f) * ln_g[j] + ln_b[j];
  dout[b * 256 + j] = fmaxf(y, 0.f);
}

// ---------------------------------------------------------------------------
// ws layout (bytes):
//   0         hbuf  [128][2][16][256] bf16  2097152  (memset 0xFF each call)
//   2129920   tb    [16][128][512] bf16     2097152
//   4227072   Q     [2048][512] bf16        2097152
//   6324224   K     [2048][512] bf16        2097152
//   8421376   V     [2048][512] bf16        2097152  -> total 10518528 bytes
// ---------------------------------------------------------------------------
extern "C" void kernel_launch(void* const* d_in, const int* in_sizes, int n_in,
                              void* d_out, int out_size, void* d_ws, size_t ws_size,
                              hipStream_t stream) {
  (void)in_sizes; (void)n_in; (void)out_size; (void)ws_size;
  const float* x     = (const float*)d_in[0];
  const float* Wih_f = (const float*)d_in[2];
  const float* Whh_f = (const float*)d_in[3];
  const float* bih_f = (const float*)d_in[4];
  const float* bhh_f = (const float*)d_in[5];
  const float* Wih_b = (const float*)d_in[6];
  const float* Whh_b = (const float*)d_in[7];
  const float* bih_b = (const float*)d_in[8];
  const float* bhh_b = (const float*)d_in[9];
  const float* Wq = (const float*)d_in[10]; const float* bq = (const float*)d_in[11];
  const float* Wk = (const float*)d_in[12]; const float* bk = (const float*)d_in[13];
  const float* Wv = (const float*)d_in[14]; const float* bv = (const float*)d_in[15];
  const float* Wo = (const float*)d_in[16]; const float* bo = (const float*)d_in[17];
  const float* W1 = (const float*)d_in[18];
  const float* b1 = (const float*)d_in[21];
  const float* g1 = (const float*)d_in[22]; const float* be1 = (const float*)d_in[23];
  const float* W2 = (const float*)d_in[24];
  const float* pb2 = (const float*)d_in[27];
  const float* g2 = (const float*)d_in[28]; const float* be2 = (const float*)d_in[29];
  const float* Wf = (const float*)d_in[30]; const float* bfv = (const float*)d_in[31];
  const float* ln_g = (const float*)d_in[32]; const float* ln_b = (const float*)d_in[33];

  float* dout = (float*)d_out;
  char* ws = (char*)d_ws;
  u32* hbuf = (u32*)(ws + 0);
  u16* tb   = (u16*)(ws + 2129920);
  u16* Qb   = (u16*)(ws + 4227072);
  u16* Kb   = (u16*)(ws + 6324224);
  u16* Vb   = (u16*)(ws + 8421376);

  (void)hipMemsetAsync(ws, 0xFF, 2097152, stream);  // poison hbuf ring
  lstm_kernel<<<32, 256, 0, stream>>>(x, Wih_f, Whh_f, bih_f, bhh_f,
                                      Wih_b, Whh_b, bih_b, bhh_b,
                                      hbuf, tb);
  qkv_kernel<<<dim3(32, 8, 3), 256, 0, stream>>>(tb, Wq, bq, Wk, bk, Wv, bv,
                                                 Qb, Kb, Vb);
  attn_kernel<<<dim3(16, 4, 2), 256, 0, stream>>>(Qb, Kb, dout + 4096);
  tail_kernel<<<16, 256, 0, stream>>>(dout + 4096, Vb, Wo, bo,
                                      W1, b1, g1, be1, W2, pb2, g2, be2,
                                      Wf, bfv, ln_g, ln_b, dout);
}

// Round 4
// 433.239 us; speedup vs baseline: 1.4243x; 1.2036x over previous
//
#include <hip/hip_runtime.h>

// ---------------------------------------------------------------------------
// SpatioTemporalBlock: biLSTM -> temporal MHA -> (collapsed) GAT -> fusion
// B=16 S=128 F=64 H=256 HEADS=4 DH=64 AH=128 D2=512
// FP32 inputs/outputs; MFMA operands converted f32->bf16 at staging.
// GAT collapses: broadcast node features => uniform alpha => dense layers.
//
// LSTM v5 = the verified 212us v1 structure with two surgical changes:
//   1. Whh/Wih B-fragments live in REGISTERS (same row mapping as v1's
//      whh_s/wih_s: row = w*16+col16 -> G = w*256+q*16+col16). Removes 10
//      of 20 ds_read_b128/lane/step + whh_s/wih_s staging + their bank
//      conflicts. No added per-step VALU (v2-v4's mistake).
//   2. x global load ISSUED before the poll; f2b+LDS store after. The
//      poll's vmcnt(0) absorbs the x-load latency v1 paid serially.
// Everything else byte-identical to v1: cooperative coalesced sc1 poll of
// the 8KB h(t) slab, LDS h_s/x_s staging, z_s round-trip, per-thread gate
// math (one element each), v1 publish geometry (32B contiguous per batch).
// hbuf ring [128 steps][2 dir][16 b][256 c] bf16, memset 0xFF per launch;
// h never hits the NaN bit pattern (bounded by sigmoid*tanh).
// ---------------------------------------------------------------------------

typedef unsigned short u16;
typedef unsigned int u32;
typedef __bf16 bf16x8 __attribute__((ext_vector_type(8)));
typedef float f32x4 __attribute__((ext_vector_type(4)));
typedef unsigned short ushort8v __attribute__((ext_vector_type(8)));
typedef unsigned int uint4v __attribute__((ext_vector_type(4)));

#define BN_INV_F 0.9999950000374997f
#define POISON 0xFFFFFFFFu

__device__ __forceinline__ float b2f(u16 u) {
  union { float f; unsigned int i; } v;
  v.i = ((unsigned int)u) << 16;
  return v.f;
}
__device__ __forceinline__ u16 f2b(float f) {
  union { float f; unsigned int i; } v;
  v.f = f;
  unsigned int x = v.i;
  unsigned int r = (x + 0x7FFFu + ((x >> 16) & 1u)) >> 16;
  return (u16)r;
}
__device__ __forceinline__ f32x4 mfma16(ushort8v a, ushort8v b, f32x4 c) {
  return __builtin_amdgcn_mfma_f32_16x16x32_bf16(
      __builtin_bit_cast(bf16x8, a), __builtin_bit_cast(bf16x8, b), c, 0, 0, 0);
}
__device__ __forceinline__ float sigm(float x) { return 1.f / (1.f + __expf(-x)); }
__device__ __forceinline__ float tanh_f(float x) {
  float e = __expf(2.f * x);
  return 1.f - 2.f / (e + 1.f);
}

// ---------------------------------------------------------------------------
// Kernel 1: bidirectional LSTM. grid = 32 blocks: dir = bx>>4, chunk q = bx&15.
// WG owns h-cols [q*16, q*16+16): 64 gate rows. Wave w handles gate w
// (n-rows w*16..w*16+15); per lane (quad, col16) the B-row is
// G = w*256 + q*16 + col16, fragments held in registers.
// Per step: issue x load -> poll h(t) (coalesced sc1, vmcnt(0) hides x) ->
// stage h_s + x_s -> barrier -> 10 MFMA (A from LDS, B from regs) -> z_s ->
// barrier -> per-thread gate math -> v1 coalesced publish.
// ---------------------------------------------------------------------------
__global__ __launch_bounds__(256) void lstm_kernel(
    const float* __restrict__ x,
    const float* __restrict__ Wih0, const float* __restrict__ Whh0,
    const float* __restrict__ bih0, const float* __restrict__ bhh0,
    const float* __restrict__ Wih1, const float* __restrict__ Whh1,
    const float* __restrict__ bih1, const float* __restrict__ bhh1,
    u32* __restrict__ hbuf,   // [128][2][16][128] u32 view (poisoned 0xFF)
    u16* __restrict__ tb)     // [16][128][512] bf16
{
  const int tid = threadIdx.x;
  const int bx = blockIdx.x;
  const int d = bx >> 4;
  const int q = bx & 15;
  const float* Wih = d ? Wih1 : Wih0;
  const float* Whh = d ? Whh1 : Whh0;
  const float* bih = d ? bih1 : bih0;
  const float* bhh = d ? bhh1 : bhh0;

  const int w = tid >> 6;
  const int ln = tid & 63;
  const int col16 = ln & 15;
  const int quad = ln >> 4;

  __shared__ u16 h_s[16][264];
  __shared__ u16 x_s[16][72];
  __shared__ float z_s[4][16][17];
  __shared__ float bias_s[64];

  // ---- stage weights into registers (bf16 fragments), v1 row mapping ----
  const int G = w * 256 + q * 16 + col16;   // row w*16+col16 of this chunk
  ushort8v whh_f[8];
#pragma unroll
  for (int kt = 0; kt < 8; kt++) {
    const float4* src = (const float4*)(Whh + G * 256 + kt * 32 + quad * 8);
    float4 v0 = src[0], v1 = src[1];
    ushort8v t8;
    t8[0] = f2b(v0.x); t8[1] = f2b(v0.y); t8[2] = f2b(v0.z); t8[3] = f2b(v0.w);
    t8[4] = f2b(v1.x); t8[5] = f2b(v1.y); t8[6] = f2b(v1.z); t8[7] = f2b(v1.w);
    whh_f[kt] = t8;
  }
  ushort8v wih_f[2];
#pragma unroll
  for (int kt = 0; kt < 2; kt++) {
    const float4* src = (const float4*)(Wih + G * 64 + kt * 32 + quad * 8);
    float4 v0 = src[0], v1 = src[1];
    ushort8v t8;
    t8[0] = f2b(v0.x); t8[1] = f2b(v0.y); t8[2] = f2b(v0.z); t8[3] = f2b(v0.w);
    t8[4] = f2b(v1.x); t8[5] = f2b(v1.y); t8[6] = f2b(v1.z); t8[7] = f2b(v1.w);
    wih_f[kt] = t8;
  }
  if (tid < 64) {
    int grow = ((tid >> 4) << 8) + q * 16 + (tid & 15);
    bias_s[tid] = bih[grow] + bhh[grow];
  }

  const int eb = tid >> 4;  // elementwise: batch
  const int ec = tid & 15;  // elementwise: h-col within chunk
  float c_reg = 0.f;

  for (int t = 0; t < 128; t++) {
    const int pos = d ? (127 - t) : t;

    // ---- issue x(pos) load (completion hidden under the poll) ----
    float4 xv = *(const float4*)(x + (eb * 128 + pos) * 64 + ec * 4);

    if (t > 0) {
      // poll full h(t): 8 u32 words per thread via 2 coalesced sc1 x4 loads
      const u32* hw = hbuf + (t * 2 + d) * 2048 + tid * 8;
      uint4v a, b;
      for (;;) {
        asm volatile(
            "global_load_dwordx4 %0, %2, off sc1\n\t"
            "global_load_dwordx4 %1, %3, off sc1\n\t"
            "s_waitcnt vmcnt(0)"
            : "=v"(a), "=v"(b)
            : "v"(hw), "v"(hw + 4)
            : "memory");
        bool ok = (a.x != POISON) & (a.y != POISON) & (a.z != POISON) &
                  (a.w != POISON) & (b.x != POISON) & (b.y != POISON) &
                  (b.z != POISON) & (b.w != POISON);
        if (ok) break;
      }
      int b_ = tid >> 4, c0 = (tid & 15) * 16;
      *(u32*)&h_s[b_][c0 + 0] = a.x;
      *(u32*)&h_s[b_][c0 + 2] = a.y;
      *(u32*)&h_s[b_][c0 + 4] = a.z;
      *(u32*)&h_s[b_][c0 + 6] = a.w;
      *(u32*)&h_s[b_][c0 + 8] = b.x;
      *(u32*)&h_s[b_][c0 + 10] = b.y;
      *(u32*)&h_s[b_][c0 + 12] = b.z;
      *(u32*)&h_s[b_][c0 + 14] = b.w;
    }
    // stage x(pos) -> bf16 LDS (data already in flight / arrived)
    {
      int f0 = ec * 4;
      x_s[eb][f0 + 0] = f2b(xv.x);
      x_s[eb][f0 + 1] = f2b(xv.y);
      x_s[eb][f0 + 2] = f2b(xv.z);
      x_s[eb][f0 + 3] = f2b(xv.w);
    }
    __syncthreads();

    f32x4 acc = {0.f, 0.f, 0.f, 0.f};
#pragma unroll
    for (int kt = 0; kt < 2; kt++) {
      ushort8v av = *(const ushort8v*)&x_s[col16][kt * 32 + quad * 8];
      acc = mfma16(av, wih_f[kt], acc);
    }
    if (t > 0) {
#pragma unroll
      for (int kt = 0; kt < 8; kt++) {
        ushort8v av = *(const ushort8v*)&h_s[col16][kt * 32 + quad * 8];
        acc = mfma16(av, whh_f[kt], acc);
      }
    }
#pragma unroll
    for (int reg = 0; reg < 4; reg++)
      z_s[w][quad * 4 + reg][col16] = acc[reg];
    __syncthreads();

    // gates: torch order i, f, g, o (f32) — one element per thread
    float zi = z_s[0][eb][ec] + bias_s[ec];
    float zf = z_s[1][eb][ec] + bias_s[16 + ec];
    float zg = z_s[2][eb][ec] + bias_s[32 + ec];
    float zo = z_s[3][eb][ec] + bias_s[48 + ec];
    float si = sigm(zi), sf = sigm(zf), so = sigm(zo);
    float tg = tanh_f(zg);
    c_reg = sf * c_reg + si * tg;
    float hv = so * tanh_f(c_reg);
    u32 my = (u32)f2b(hv);
    u32 hi = __shfl_down((int)my, 1);  // partner col (ec+1), same wave
    if ((ec & 1) == 0) {
      u32 word = my | (hi << 16);
      *(u32*)&tb[(eb * 128 + pos) * 512 + d * 256 + q * 16 + ec] = word;
      if (t < 127) {
        u32* dst = hbuf + ((t + 1) * 2 + d) * 2048 + eb * 128 + (q * 16 + ec) / 2;
        __hip_atomic_store(dst, word, __ATOMIC_RELAXED,
                           __HIP_MEMORY_SCOPE_AGENT);
      }
    }
    // no extra barrier: next-iter writes touch x_s/h_s only, whose reads all
    // completed before the z_s barrier above.
  }
}

// ---------------------------------------------------------------------------
// Kernel 2: QKV projection.  out = t @ W^T + bias, M=2048 N=512 K=512.
// grid = (32 Mtiles, 8 Ntiles, 3 which). Q,K,V stored bf16.
// ---------------------------------------------------------------------------
__global__ __launch_bounds__(256) void qkv_kernel(
    const u16* __restrict__ tb,
    const float* __restrict__ Wq, const float* __restrict__ bq,
    const float* __restrict__ Wk, const float* __restrict__ bk,
    const float* __restrict__ Wv, const float* __restrict__ bv,
    u16* __restrict__ Qb, u16* __restrict__ Kb, u16* __restrict__ Vb)
{
  const int tid = threadIdx.x;
  const int bxm = blockIdx.x, byn = blockIdx.y, bz = blockIdx.z;
  const float* W = (bz == 0) ? Wq : ((bz == 1) ? Wk : Wv);
  const float* bias = (bz == 0) ? bq : ((bz == 1) ? bk : bv);
  u16* outp = (bz == 0) ? Qb : ((bz == 1) ? Kb : Vb);

  __shared__ u16 a_s[64][40];
  __shared__ u16 b_s[64][40];
  const int w = tid >> 6, ln = tid & 63, col16 = ln & 15, quad = ln >> 4;

  f32x4 acc[4];
#pragma unroll
  for (int n = 0; n < 4; n++) acc[n] = (f32x4){0.f, 0.f, 0.f, 0.f};

  for (int kt = 0; kt < 16; kt++) {
    int r = tid >> 2, seg = tid & 3;
    *(ushort8v*)&a_s[r][seg * 8] =
        *(const ushort8v*)(tb + (bxm * 64 + r) * 512 + kt * 32 + seg * 8);
    const float4* wsrc = (const float4*)(W + (byn * 64 + r) * 512 + kt * 32 + seg * 8);
    float4 w0 = wsrc[0], w1 = wsrc[1];
    b_s[r][seg * 8 + 0] = f2b(w0.x);
    b_s[r][seg * 8 + 1] = f2b(w0.y);
    b_s[r][seg * 8 + 2] = f2b(w0.z);
    b_s[r][seg * 8 + 3] = f2b(w0.w);
    b_s[r][seg * 8 + 4] = f2b(w1.x);
    b_s[r][seg * 8 + 5] = f2b(w1.y);
    b_s[r][seg * 8 + 6] = f2b(w1.z);
    b_s[r][seg * 8 + 7] = f2b(w1.w);
    __syncthreads();
    ushort8v av = *(const ushort8v*)&a_s[w * 16 + col16][quad * 8];
#pragma unroll
    for (int n = 0; n < 4; n++) {
      ushort8v bvv = *(const ushort8v*)&b_s[n * 16 + col16][quad * 8];
      acc[n] = mfma16(av, bvv, acc[n]);
    }
    __syncthreads();
  }
#pragma unroll
  for (int n = 0; n < 4; n++) {
    float bs = bias[byn * 64 + n * 16 + col16];
#pragma unroll
    for (int reg = 0; reg < 4; reg++) {
      int row = bxm * 64 + w * 16 + quad * 4 + reg;
      outp[row * 512 + byn * 64 + n * 16 + col16] = f2b(acc[n][reg] + bs);
    }
  }
}

// ---------------------------------------------------------------------------
// Kernel 3: scores + softmax -> attn (d_out, f32). grid = (16 b, 4 h, 2 qhalf).
// Epilogue: per-row inv staged in LDS, cooperative coalesced float4 stores.
// ---------------------------------------------------------------------------
__global__ __launch_bounds__(256) void attn_kernel(
    const u16* __restrict__ Qb, const u16* __restrict__ Kb,
    float* __restrict__ attn_out)
{
  const int b = blockIdx.x, h = blockIdx.y, half = blockIdx.z;
  const int tid = threadIdx.x;
  __shared__ __align__(16) char smem[52224];
  __shared__ float inv_s[64];
  u16 (*q_s)[136] = (u16(*)[136])smem;
  u16 (*k_s)[136] = (u16(*)[136])(smem + 17408);
  float (*sc)[132] = (float(*)[132])smem;  // reused after MFMA

  const int w = tid >> 6, ln = tid & 63, col16 = ln & 15, quad = ln >> 4;
  {
    int r = tid >> 2, seg = tid & 3;
    const u16* src = Qb + (b * 128 + half * 64 + r) * 512 + h * 128 + seg * 32;
#pragma unroll
    for (int i = 0; i < 4; i++)
      *(ushort8v*)&q_s[r][seg * 32 + i * 8] = *(const ushort8v*)(src + i * 8);
    int r2 = tid >> 1, sg = tid & 1;
    const u16* src2 = Kb + (b * 128 + r2) * 512 + h * 128 + sg * 64;
#pragma unroll
    for (int i = 0; i < 8; i++)
      *(ushort8v*)&k_s[r2][sg * 64 + i * 8] = *(const ushort8v*)(src2 + i * 8);
  }
  __syncthreads();

  f32x4 acc[8];
#pragma unroll
  for (int n = 0; n < 8; n++) acc[n] = (f32x4){0.f, 0.f, 0.f, 0.f};
#pragma unroll
  for (int kd = 0; kd < 4; kd++) {
    ushort8v av = *(const ushort8v*)&q_s[w * 16 + col16][kd * 32 + quad * 8];
#pragma unroll
    for (int n = 0; n < 8; n++) {
      ushort8v bvv = *(const ushort8v*)&k_s[n * 16 + col16][kd * 32 + quad * 8];
      acc[n] = mfma16(av, bvv, acc[n]);
    }
  }
  __syncthreads();  // done with q_s/k_s before overwriting with sc
  const float scale = 0.08838834764831845f;  // 1/sqrt(128)
#pragma unroll
  for (int n = 0; n < 8; n++)
#pragma unroll
    for (int reg = 0; reg < 4; reg++)
      sc[w * 16 + quad * 4 + reg][n * 16 + col16] = acc[n][reg] * scale;
  __syncthreads();

  const int row = tid >> 2, p = tid & 3;
  float m = -1e30f;
  for (int c0 = 0; c0 < 32; c0++) m = fmaxf(m, sc[row][p * 32 + c0]);
  m = fmaxf(m, __shfl_xor(m, 1));
  m = fmaxf(m, __shfl_xor(m, 2));
  float s = 0.f;
  for (int c0 = 0; c0 < 32; c0++) {
    float e = __expf(sc[row][p * 32 + c0] - m);
    sc[row][p * 32 + c0] = e;
    s += e;
  }
  s += __shfl_xor(s, 1);
  s += __shfl_xor(s, 2);
  if (p == 0) inv_s[row] = 1.f / s;
  __syncthreads();

  // cooperative coalesced store: 64 rows x 128 f32
  float* obase = attn_out + (size_t)((b * 4 + h) * 128 + half * 64) * 128;
#pragma unroll
  for (int it = 0; it < 8; it++) {
    int idx = tid + it * 256;     // 0..2047
    int r = idx >> 5;             // row 0..63
    int c4 = idx & 31;            // float4 index 0..31
    float4 ev = *(float4*)&sc[r][c4 * 4];
    float iv = inv_s[r];
    float4 ov = {ev.x * iv, ev.y * iv, ev.z * iv, ev.w * iv};
    *(float4*)&obase[r * 128 + c4 * 4] = ov;
  }
}

// ---------------------------------------------------------------------------
// Kernel 4 (merged aolast+fuse): ao (q=127 only), last = ao@Wo^T+bo,
// collapsed GAT (2 dense layers), fusion Linear + LayerNorm + ReLU.
// grid = 16 (batch), 256 threads.
// ---------------------------------------------------------------------------
__global__ __launch_bounds__(256) void tail_kernel(
    const float* __restrict__ attn, const u16* __restrict__ Vb,
    const float* __restrict__ Wo, const float* __restrict__ bo,
    const float* __restrict__ W1, const float* __restrict__ b1,
    const float* __restrict__ g1, const float* __restrict__ be1,
    const float* __restrict__ W2, const float* __restrict__ pb2,
    const float* __restrict__ g2, const float* __restrict__ be2,
    const float* __restrict__ Wf, const float* __restrict__ bfv,
    const float* __restrict__ ln_g, const float* __restrict__ ln_b,
    float* __restrict__ dout)
{
  const int b = blockIdx.x, tid = threadIdx.x;
  __shared__ float arow[4][128];
  __shared__ float ao_s[512];
  __shared__ float last_s[512];
  __shared__ float h_s2[256];
  __shared__ float red_s[4];

  // ---- ao row (q=127) ----
#pragma unroll
  for (int e = 0; e < 2; e++) {
    int idx = tid + e * 256;
    int h = idx >> 7, k = idx & 127;
    arow[h][k] = attn[((b * 4 + h) * 128 + 127) * 128 + k];
  }
  __syncthreads();
#pragma unroll
  for (int pass = 0; pass < 2; pass++) {
    int d2 = tid + pass * 256;
    int hh = d2 >> 7;
    float acc = 0.f;
    for (int k = 0; k < 128; k++)
      acc += arow[hh][k] * b2f(Vb[(b * 128 + k) * 512 + d2]);
    ao_s[d2] = acc;
  }
  __syncthreads();
  // ---- last = ao @ Wo^T + bo ----
#pragma unroll
  for (int pass = 0; pass < 2; pass++) {
    int j = tid + pass * 256;
    float acc = bo[j];
    const float4* Wo4 = (const float4*)(Wo + j * 512);
    for (int k4 = 0; k4 < 128; k4++) {
      float4 wv = Wo4[k4];
      acc += ao_s[k4 * 4 + 0] * wv.x + ao_s[k4 * 4 + 1] * wv.y +
             ao_s[k4 * 4 + 2] * wv.z + ao_s[k4 * 4 + 3] * wv.w;
    }
    last_s[j] = acc;
  }
  __syncthreads();

  // ---- collapsed GAT layer 1 ----
  const int j = tid;
  float acc = 0.f;
  for (int k = 0; k < 512; k++) acc += last_s[k] * W1[k * 256 + j];
  float u = (acc + b1[j]) * BN_INV_F * g1[j] + be1[j];
  float h1 = u > 0.f ? u : expm1f(u);
  h_s2[j] = h1;
  __syncthreads();

  // ---- collapsed GAT layer 2 ----
  float acc2 = 0.f;
  for (int k = 0; k < 256; k++) acc2 += h_s2[k] * W2[k * 256 + j];
  float u2 = (acc2 + pb2[j]) * BN_INV_F * g2[j] + be2[j];
  float sp = u2 > 0.f ? u2 : expm1f(u2);
  __syncthreads();
  h_s2[j] = sp;
  __syncthreads();

  // ---- fusion Linear ----
  float f = bfv[j];
  const float4* Wf4 = (const float4*)(Wf + j * 768);
  for (int k4 = 0; k4 < 128; k4++) {
    float4 wv = Wf4[k4];
    f += last_s[k4 * 4 + 0] * wv.x + last_s[k4 * 4 + 1] * wv.y +
         last_s[k4 * 4 + 2] * wv.z + last_s[k4 * 4 + 3] * wv.w;
  }
  for (int k4 = 0; k4 < 64; k4++) {
    float4 wv = Wf4[128 + k4];
    f += h_s2[k4 * 4 + 0] * wv.x + h_s2[k4 * 4 + 1] * wv.y +
         h_s2[k4 * 4 + 2] * wv.z + h_s2[k4 * 4 + 3] * wv.w;
  }

  // ---- LayerNorm + ReLU ----
  float v = f;
#pragma unroll
  for (int o = 32; o > 0; o >>= 1) v += __shfl_xor(v, o);
  if ((tid & 63) == 0) red_s[tid >> 6] = v;
  __syncthreads();
  float mu = (red_s[0] + red_s[1] + red_s[2] + red_s[3]) * (1.f / 256.f);
  float dv = f - mu;
  float vv = dv * dv;
#pragma unroll
  for (int o = 32; o > 0; o >>= 1) vv += __shfl_xor(vv, o);
  __syncthreads();
  if ((tid & 63) == 0) red_s[tid >> 6] = vv;
  __syncthreads();
  float var = (red_s[0] + red_s[1] + red_s[2] + red_s[3]) * (1.f / 256.f);
  float y = dv * rsqrtf(var + 1e-5f) * ln_g[j] + ln_b[j];
  dout[b * 256 + j] = fmaxf(y, 0.f);
}

// ---------------------------------------------------------------------------
// ws layout (bytes):
//   0         hbuf  [128][2][16][256] bf16  2097152  (memset 0xFF each call)
//   2129920   tb    [16][128][512] bf16     2097152
//   4227072   Q     [2048][512] bf16        2097152
//   6324224   K     [2048][512] bf16        2097152
//   8421376   V     [2048][512] bf16        2097152  -> total 10518528 bytes
// ---------------------------------------------------------------------------
extern "C" void kernel_launch(void* const* d_in, const int* in_sizes, int n_in,
                              void* d_out, int out_size, void* d_ws, size_t ws_size,
                              hipStream_t stream) {
  (void)in_sizes; (void)n_in; (void)out_size; (void)ws_size;
  const float* x     = (const float*)d_in[0];
  const float* Wih_f = (const float*)d_in[2];
  const float* Whh_f = (const float*)d_in[3];
  const float* bih_f = (const float*)d_in[4];
  const float* bhh_f = (const float*)d_in[5];
  const float* Wih_b = (const float*)d_in[6];
  const float* Whh_b = (const float*)d_in[7];
  const float* bih_b = (const float*)d_in[8];
  const float* bhh_b = (const float*)d_in[9];
  const float* Wq = (const float*)d_in[10]; const float* bq = (const float*)d_in[11];
  const float* Wk = (const float*)d_in[12]; const float* bk = (const float*)d_in[13];
  const float* Wv = (const float*)d_in[14]; const float* bv = (const float*)d_in[15];
  const float* Wo = (const float*)d_in[16]; const float* bo = (const float*)d_in[17];
  const float* W1 = (const float*)d_in[18];
  const float* b1 = (const float*)d_in[21];
  const float* g1 = (const float*)d_in[22]; const float* be1 = (const float*)d_in[23];
  const float* W2 = (const float*)d_in[24];
  const float* pb2 = (const float*)d_in[27];
  const float* g2 = (const float*)d_in[28]; const float* be2 = (const float*)d_in[29];
  const float* Wf = (const float*)d_in[30]; const float* bfv = (const float*)d_in[31];
  const float* ln_g = (const float*)d_in[32]; const float* ln_b = (const float*)d_in[33];

  float* dout = (float*)d_out;
  char* ws = (char*)d_ws;
  u32* hbuf = (u32*)(ws + 0);
  u16* tb   = (u16*)(ws + 2129920);
  u16* Qb   = (u16*)(ws + 4227072);
  u16* Kb   = (u16*)(ws + 6324224);
  u16* Vb   = (u16*)(ws + 8421376);

  (void)hipMemsetAsync(ws, 0xFF, 2097152, stream);  // poison hbuf ring
  lstm_kernel<<<32, 256, 0, stream>>>(x, Wih_f, Whh_f, bih_f, bhh_f,
                                      Wih_b, Whh_b, bih_b, bhh_b,
                                      hbuf, tb);
  qkv_kernel<<<dim3(32, 8, 3), 256, 0, stream>>>(tb, Wq, bq, Wk, bk, Wv, bv,
                                                 Qb, Kb, Vb);
  attn_kernel<<<dim3(16, 4, 2), 256, 0, stream>>>(Qb, Kb, dout + 4096);
  tail_kernel<<<16, 256, 0, stream>>>(dout + 4096, Vb, Wo, bo,
                                      W1, b1, g1, be1, W2, pb2, g2, be2,
                                      Wf, bfv, ln_g, ln_b, dout);
}